// Round 2
// baseline (275.749 us; speedup 1.0000x reference)
//
#include <hip/hip_runtime.h>

#define DM 768
#define NHEAD 8
#define HDIM 96
#define NB 8
#define SEQ 8192
#define NA 512
#define MROW (NB*NA)      // 4096 anchor rows total
#define NQKV (3*DM)       // 2304

typedef __attribute__((ext_vector_type(4))) float f32x4;
typedef __attribute__((ext_vector_type(8))) short s16x8;

static __device__ __forceinline__ unsigned short f2bf(float x) {
  unsigned int u = __float_as_uint(x);
  u += 0x7fffu + ((u >> 16) & 1u);          // RNE
  return (unsigned short)(u >> 16);
}
static __device__ __forceinline__ float bf2f(unsigned short h) {
  return __uint_as_float(((unsigned int)h) << 16);
}
static __device__ __forceinline__ void split2(float x, unsigned short& hi, unsigned short& lo) {
  hi = f2bf(x);
  lo = f2bf(x - bf2f(hi));                  // exact residual in fp32
}

static __device__ __forceinline__ void gld_lds16(const void* g, void* l) {
  __builtin_amdgcn_global_load_lds(
      (const __attribute__((address_space(1))) unsigned int*)g,
      (__attribute__((address_space(3))) unsigned int*)l, 16, 0, 0);
}

// ---------------- fast zero-fill of the output (replaces 1.77 TB/s rocclr fill) ----------
__global__ __launch_bounds__(256) void fill_zero(f32x4* __restrict__ p, int n4) {
  const f32x4 z = {0.f, 0.f, 0.f, 0.f};
  int i = blockIdx.x * 256 + threadIdx.x;
  const int stride = gridDim.x * 256;
  for (; i < n4; i += stride) __builtin_nontemporal_store(z, p + i);
}

// ---------------- weights -> bf16 hi/lo split ----------------
__global__ __launch_bounds__(256) void prep_weights(
    const float* __restrict__ wq, const float* __restrict__ wk,
    const float* __restrict__ wv, const float* __restrict__ wo,
    unsigned short* __restrict__ w1h, unsigned short* __restrict__ w1l,
    unsigned short* __restrict__ woh, unsigned short* __restrict__ wol)
{
  int i = blockIdx.x * 256 + threadIdx.x;
  const int T1 = NQKV * DM;
  const int TW = DM * DM;
  if (i < T1) {
    float v = (i < TW) ? wq[i] : (i < 2*TW) ? wk[i - TW] : wv[i - 2*TW];
    unsigned short h, l; split2(v, h, l);
    w1h[i] = h; w1l[i] = l;
  } else if (i < T1 + TW) {
    int j = i - T1;
    unsigned short h, l; split2(wo[j], h, l);
    woh[j] = h; wol[j] = l;
  }
}

// ---------------- gather anchors + LayerNorm -> x hi/lo ----------------
__global__ __launch_bounds__(256) void gather_ln(
    const float* __restrict__ hs, const int* __restrict__ anc,
    const float* __restrict__ gam, const float* __restrict__ bet,
    unsigned short* __restrict__ xh, unsigned short* __restrict__ xl)
{
  int r = blockIdx.x;                 // 0..4095  (b,a)
  int b = r >> 9, a = r & (NA - 1);
  int idx = anc[b * NA + a];
  const float* src = hs + ((size_t)b * SEQ + idx) * DM;
  int t = threadIdx.x;
  float e0 = src[t], e1 = src[t + 256], e2 = src[t + 512];
  float s = e0 + e1 + e2;
  float ss = e0*e0 + e1*e1 + e2*e2;
  #pragma unroll
  for (int o = 1; o < 64; o <<= 1) { s += __shfl_xor(s, o); ss += __shfl_xor(ss, o); }
  __shared__ float red[8];
  int w = t >> 6, lane = t & 63;
  if (lane == 0) { red[w] = s; red[4 + w] = ss; }
  __syncthreads();
  s  = red[0] + red[1] + red[2] + red[3];
  ss = red[4] + red[5] + red[6] + red[7];
  float mu = s * (1.f / DM);
  float var = ss * (1.f / DM) - mu * mu;   // biased, matches jnp.var
  float rstd = rsqrtf(var + 1e-5f);
  size_t base = (size_t)r * DM;
  #pragma unroll
  for (int p = 0; p < 3; ++p) {
    int c = t + p * 256;
    float e = (p == 0) ? e0 : (p == 1) ? e1 : e2;
    float y = (e - mu) * rstd * gam[c] + bet[c];
    unsigned short h, l; split2(y, h, l);
    xh[base + c] = h; xl[base + c] = l;
  }
}

// ---------------- 128x128 split-bf16 NT GEMM (A[M][K], B[N][K]) ----------------
// EPI=1: QKV epilogue (bias + split to q/k/vT hi/lo buffers)
// EPI=2: out-proj epilogue (bias + scatter to d_out at anchor rows)
template<int EPI>
__global__ __launch_bounds__(256, 2) void gemm128(
    const unsigned short* __restrict__ Ah, const unsigned short* __restrict__ Al,
    const unsigned short* __restrict__ Bh, const unsigned short* __restrict__ Bl,
    const float* __restrict__ biasq, const float* __restrict__ biask, const float* __restrict__ biasv,
    unsigned short* __restrict__ qh, unsigned short* __restrict__ ql,
    unsigned short* __restrict__ kh, unsigned short* __restrict__ kl,
    unsigned short* __restrict__ vh, unsigned short* __restrict__ vl,
    const float* __restrict__ biaso, const int* __restrict__ anc,
    float* __restrict__ outp)
{
  __shared__ unsigned short sAh[128 * 32], sAl[128 * 32], sBh[128 * 32], sBl[128 * 32];
  const int tid = threadIdx.x, lane = tid & 63, w = tid >> 6;
  const int wr = w >> 1, wc = w & 1;
  const int m0 = blockIdx.y * 128, n0 = blockIdx.x * 128;
  const int rsel = lane & 15, kg = lane >> 4;
  f32x4 acc[4][4] = {};

  for (int k0 = 0; k0 < DM; k0 += 32) {
    __syncthreads();
    // stage: granule g (16B) holds row=g>>2, kslot=(g&3)^((row>>1)&3) (bank swizzle)
    #pragma unroll
    for (int c = 0; c < 2; ++c) {
      const int gg = w * 128 + c * 64;           // wave-uniform granule base
      const int g = gg + lane;
      const int row = g >> 2, slot = g & 3;
      const int kk = k0 + ((slot ^ ((row >> 1) & 3)) << 3);
      const size_t aoff = (size_t)(m0 + row) * DM + kk;
      const size_t boff = (size_t)(n0 + row) * DM + kk;
      gld_lds16(Ah + aoff, sAh + gg * 8);
      gld_lds16(Al + aoff, sAl + gg * 8);
      gld_lds16(Bh + boff, sBh + gg * 8);
      gld_lds16(Bl + boff, sBl + gg * 8);
    }
    __syncthreads();
    s16x8 afh[4], afl[4], bfh[4], bfl[4];
    #pragma unroll
    for (int i = 0; i < 4; ++i) {
      const int row = wr * 64 + i * 16 + rsel;
      const int aoff = row * 32 + ((kg ^ ((row >> 1) & 3)) << 3);
      afh[i] = *reinterpret_cast<const s16x8*>(sAh + aoff);
      afl[i] = *reinterpret_cast<const s16x8*>(sAl + aoff);
      const int col = wc * 64 + i * 16 + rsel;
      const int boff2 = col * 32 + ((kg ^ ((col >> 1) & 3)) << 3);
      bfh[i] = *reinterpret_cast<const s16x8*>(sBh + boff2);
      bfl[i] = *reinterpret_cast<const s16x8*>(sBl + boff2);
    }
    #pragma unroll
    for (int i = 0; i < 4; ++i)
      #pragma unroll
      for (int j = 0; j < 4; ++j) {
        acc[i][j] = __builtin_amdgcn_mfma_f32_16x16x32_bf16(afh[i], bfh[j], acc[i][j], 0, 0, 0);
        acc[i][j] = __builtin_amdgcn_mfma_f32_16x16x32_bf16(afh[i], bfl[j], acc[i][j], 0, 0, 0);
        acc[i][j] = __builtin_amdgcn_mfma_f32_16x16x32_bf16(afl[i], bfh[j], acc[i][j], 0, 0, 0);
      }
  }

  #pragma unroll
  for (int i = 0; i < 4; ++i)
    #pragma unroll
    for (int j = 0; j < 4; ++j)
      #pragma unroll
      for (int r = 0; r < 4; ++r) {
        const int row = m0 + wr * 64 + i * 16 + kg * 4 + r;   // C/D: row=(l>>4)*4+reg
        const int col = n0 + wc * 64 + j * 16 + rsel;          //      col=l&15
        const float v = acc[i][j][r];
        const int b = row >> 9, a = row & (NA - 1);
        if (EPI == 1) {
          const int sec = (col >= 2 * DM) ? 2 : (col >= DM ? 1 : 0);
          const int f = col - sec * DM;
          const int hh = f / HDIM, d = f - hh * HDIM;
          const float* bp = (sec == 0) ? biasq : (sec == 1) ? biask : biasv;
          const float val = v + bp[f];
          unsigned short hi, lo; split2(val, hi, lo);
          const int bhh = b * NHEAD + hh;
          if (sec == 0)      { const size_t o = ((size_t)bhh * NA + a) * HDIM + d; qh[o] = hi; ql[o] = lo; }
          else if (sec == 1) { const size_t o = ((size_t)bhh * NA + a) * HDIM + d; kh[o] = hi; kl[o] = lo; }
          else               { const size_t o = ((size_t)bhh * HDIM + d) * NA + a; vh[o] = hi; vl[o] = lo; } // V transposed
        } else {
          const int sidx = anc[b * NA + a];
          outp[((size_t)b * SEQ + sidx) * DM + col] = v + biaso[col];
        }
      }
}

// ---------------- fused attention: per (b,h,64-row Q tile), barrier-free ----------------
__global__ __launch_bounds__(256, 1) void attn_fused(
    const unsigned short* __restrict__ qh, const unsigned short* __restrict__ ql,
    const unsigned short* __restrict__ kh, const unsigned short* __restrict__ kl,
    const unsigned short* __restrict__ vh, const unsigned short* __restrict__ vl,
    unsigned short* __restrict__ oh, unsigned short* __restrict__ ol)
{
  __shared__ unsigned int S[64 * 512];   // fp32 scores, then packed P (hi<<16|lo). 128 KiB
  const int blk = blockIdx.x;
  const int qt = blk & 7, bh = blk >> 3;
  const int b = bh >> 3, h = bh & 7;
  const int tid = threadIdx.x, lane = tid & 63, w = tid >> 6;
  const int rsel = lane & 15, kg = lane >> 4;
  const int q0 = qt * 64;

  // Q fragments for this wave's 16 rows
  s16x8 qfh[3], qfl[3];
  {
    const size_t qrow = (size_t)bh * NA + q0 + w * 16 + rsel;
    const unsigned short* qp  = qh + qrow * HDIM + kg * 8;
    const unsigned short* qp2 = ql + qrow * HDIM + kg * 8;
    #pragma unroll
    for (int kc = 0; kc < 3; ++kc) {
      qfh[kc] = *reinterpret_cast<const s16x8*>(qp  + kc * 32);
      qfl[kc] = *reinterpret_cast<const s16x8*>(qp2 + kc * 32);
    }
  }
  const float scale = 0.10206207261596575f;  // 1/sqrt(96)
  const unsigned short* kb_h = kh + (size_t)bh * NA * HDIM;
  const unsigned short* kb_l = kl + (size_t)bh * NA * HDIM;

  // S = Q K^T * scale ; wave w owns score rows w*16..w*16+15
  for (int ct = 0; ct < 32; ++ct) {
    f32x4 acc = {0.f, 0.f, 0.f, 0.f};
    const unsigned short* kp  = kb_h + (size_t)(ct * 16 + rsel) * HDIM + kg * 8;
    const unsigned short* kp2 = kb_l + (size_t)(ct * 16 + rsel) * HDIM + kg * 8;
    #pragma unroll
    for (int kc = 0; kc < 3; ++kc) {
      s16x8 kfh = *reinterpret_cast<const s16x8*>(kp  + kc * 32);
      s16x8 kfl = *reinterpret_cast<const s16x8*>(kp2 + kc * 32);
      acc = __builtin_amdgcn_mfma_f32_16x16x32_bf16(qfh[kc], kfh, acc, 0, 0, 0);
      acc = __builtin_amdgcn_mfma_f32_16x16x32_bf16(qfh[kc], kfl, acc, 0, 0, 0);
      acc = __builtin_amdgcn_mfma_f32_16x16x32_bf16(qfl[kc], kfh, acc, 0, 0, 0);
    }
    #pragma unroll
    for (int r = 0; r < 4; ++r) {
      int row = w * 16 + kg * 4 + r;
      int col = ct * 16 + rsel;
      S[row * 512 + (col ^ ((row & 7) << 2))] = __float_as_uint(acc[r] * scale);  // col swizzle (banks)
    }
  }

  // wave-local softmax: 4 lanes per row, 128 cols each; pack P as bf16 hi/lo in place
  float inv;
  {
    const int row = w * 16 + (lane >> 2);
    const int sub = lane & 3;
    const int srow = (row & 7) << 2;
    unsigned int* rowp = &S[row * 512];
    float mx = -3.0e38f;
    #pragma unroll 8
    for (int i = 0; i < 32; ++i) {
      int c = sub * 128 + i * 4;
      uint4 u = *reinterpret_cast<const uint4*>(rowp + (c ^ srow));
      mx = fmaxf(mx, fmaxf(fmaxf(__uint_as_float(u.x), __uint_as_float(u.y)),
                           fmaxf(__uint_as_float(u.z), __uint_as_float(u.w))));
    }
    mx = fmaxf(mx, __shfl_xor(mx, 1));
    mx = fmaxf(mx, __shfl_xor(mx, 2));
    float sum = 0.f;
    #pragma unroll 8
    for (int i = 0; i < 32; ++i) {
      int c = sub * 128 + i * 4;
      uint4 u = *reinterpret_cast<const uint4*>(rowp + (c ^ srow));
      float p0 = __expf(__uint_as_float(u.x) - mx);
      float p1 = __expf(__uint_as_float(u.y) - mx);
      float p2 = __expf(__uint_as_float(u.z) - mx);
      float p3 = __expf(__uint_as_float(u.w) - mx);
      sum += p0 + p1 + p2 + p3;
      unsigned short h0,l0,h1,l1,h2,l2,h3,l3;
      split2(p0,h0,l0); split2(p1,h1,l1); split2(p2,h2,l2); split2(p3,h3,l3);
      uint4 pk;
      pk.x = ((unsigned)h0 << 16) | l0;
      pk.y = ((unsigned)h1 << 16) | l1;
      pk.z = ((unsigned)h2 << 16) | l2;
      pk.w = ((unsigned)h3 << 16) | l3;
      *reinterpret_cast<uint4*>(rowp + (c ^ srow)) = pk;
    }
    sum += __shfl_xor(sum, 1);
    sum += __shfl_xor(sum, 2);
    inv = 1.f / sum;
  }

  // O = P V  (V stored transposed [bh][d][a] -> NT MFMA), divide by row sum at the end
  const unsigned short* vb_h = vh + (size_t)bh * HDIM * NA;
  const unsigned short* vb_l = vl + (size_t)bh * HDIM * NA;
  f32x4 acc[6] = {};
  {
    const int row = w * 16 + rsel;
    const int srow = (row & 7) << 2;
    const unsigned int* rowp = &S[row * 512];
    for (int kc = 0; kc < 16; ++kc) {
      int c = kc * 32 + kg * 8;
      uint4 ua = *reinterpret_cast<const uint4*>(rowp + ((c) ^ srow));
      uint4 ub = *reinterpret_cast<const uint4*>(rowp + ((c + 4) ^ srow));
      s16x8 ph, pl;
      ph[0] = (short)(ua.x >> 16); pl[0] = (short)(ua.x & 0xffff);
      ph[1] = (short)(ua.y >> 16); pl[1] = (short)(ua.y & 0xffff);
      ph[2] = (short)(ua.z >> 16); pl[2] = (short)(ua.z & 0xffff);
      ph[3] = (short)(ua.w >> 16); pl[3] = (short)(ua.w & 0xffff);
      ph[4] = (short)(ub.x >> 16); pl[4] = (short)(ub.x & 0xffff);
      ph[5] = (short)(ub.y >> 16); pl[5] = (short)(ub.y & 0xffff);
      ph[6] = (short)(ub.z >> 16); pl[6] = (short)(ub.z & 0xffff);
      ph[7] = (short)(ub.w >> 16); pl[7] = (short)(ub.w & 0xffff);
      #pragma unroll
      for (int nt = 0; nt < 6; ++nt) {
        const unsigned short* vp  = vb_h + (size_t)(nt * 16 + rsel) * NA + c;
        const unsigned short* vp2 = vb_l + (size_t)(nt * 16 + rsel) * NA + c;
        s16x8 vfh = *reinterpret_cast<const s16x8*>(vp);
        s16x8 vfl = *reinterpret_cast<const s16x8*>(vp2);
        acc[nt] = __builtin_amdgcn_mfma_f32_16x16x32_bf16(ph, vfh, acc[nt], 0, 0, 0);
        acc[nt] = __builtin_amdgcn_mfma_f32_16x16x32_bf16(ph, vfl, acc[nt], 0, 0, 0);
        acc[nt] = __builtin_amdgcn_mfma_f32_16x16x32_bf16(pl, vfh, acc[nt], 0, 0, 0);
      }
    }
  }

  #pragma unroll
  for (int r = 0; r < 4; ++r) {
    float rinv = __shfl(inv, ((kg * 4 + r) << 2));   // row sums live at lanes 4*rowlocal
    int rowg = b * NA + q0 + w * 16 + kg * 4 + r;
    #pragma unroll
    for (int nt = 0; nt < 6; ++nt) {
      float val = acc[nt][r] * rinv;
      unsigned short hi, lo; split2(val, hi, lo);
      size_t o = (size_t)rowg * DM + h * HDIM + nt * 16 + rsel;
      oh[o] = hi; ol[o] = lo;
    }
  }
}

extern "C" void kernel_launch(void* const* d_in, const int* in_sizes, int n_in,
                              void* d_out, int out_size, void* d_ws, size_t ws_size,
                              hipStream_t stream)
{
  const float* hs   = (const float*)d_in[0];
  const int*   anc  = (const int*)d_in[1];
  const float* ln_g = (const float*)d_in[2];
  const float* ln_b = (const float*)d_in[3];
  const float* wq = (const float*)d_in[4];
  const float* bq = (const float*)d_in[5];
  const float* wk = (const float*)d_in[6];
  const float* bk = (const float*)d_in[7];
  const float* wv = (const float*)d_in[8];
  const float* bv = (const float*)d_in[9];
  const float* wo = (const float*)d_in[10];
  const float* bo = (const float*)d_in[11];
  float* outp = (float*)d_out;

  char* ws = (char*)d_ws;
  size_t off = 0;
  auto take = [&](size_t bytes) { char* p = ws + off; off += (bytes + 255) & ~(size_t)255; return p; };
  unsigned short* xh  = (unsigned short*)take((size_t)MROW * DM * 2);
  unsigned short* xl  = (unsigned short*)take((size_t)MROW * DM * 2);
  unsigned short* w1h = (unsigned short*)take((size_t)NQKV * DM * 2);
  unsigned short* w1l = (unsigned short*)take((size_t)NQKV * DM * 2);
  unsigned short* woh = (unsigned short*)take((size_t)DM * DM * 2);
  unsigned short* wol = (unsigned short*)take((size_t)DM * DM * 2);
  const size_t qkvsz = (size_t)NB * NHEAD * NA * HDIM * 2;
  unsigned short* qhb = (unsigned short*)take(qkvsz);
  unsigned short* qlb = (unsigned short*)take(qkvsz);
  unsigned short* khb = (unsigned short*)take(qkvsz);
  unsigned short* klb = (unsigned short*)take(qkvsz);
  unsigned short* vhb = (unsigned short*)take(qkvsz);
  unsigned short* vlb = (unsigned short*)take(qkvsz);
  unsigned short* ohb = (unsigned short*)take((size_t)MROW * DM * 2);
  unsigned short* olb = (unsigned short*)take((size_t)MROW * DM * 2);
  // total ws use ~72.4 MB

  fill_zero<<<2048, 256, 0, stream>>>((f32x4*)outp, out_size / 4);
  prep_weights<<<(NQKV * DM + DM * DM + 255) / 256, 256, 0, stream>>>(
      wq, wk, wv, wo, w1h, w1l, woh, wol);
  gather_ln<<<MROW, 256, 0, stream>>>(hs, anc, ln_g, ln_b, xh, xl);
  gemm128<1><<<dim3(NQKV / 128, MROW / 128), 256, 0, stream>>>(
      xh, xl, w1h, w1l, bq, bk, bv, qhb, qlb, khb, klb, vhb, vlb,
      nullptr, nullptr, nullptr);
  attn_fused<<<NB * NHEAD * 8, 256, 0, stream>>>(qhb, qlb, khb, klb, vhb, vlb, ohb, olb);
  gemm128<2><<<dim3(DM / 128, MROW / 128), 256, 0, stream>>>(
      ohb, olb, woh, wol, nullptr, nullptr, nullptr,
      nullptr, nullptr, nullptr, nullptr, nullptr, nullptr, bo, anc, outp);
}

// Round 3
// 256.838 us; speedup vs baseline: 1.0736x; 1.0736x over previous
//
#include <hip/hip_runtime.h>

#define DM 768
#define NHEAD 8
#define HDIM 96
#define NB 8
#define SEQ 8192
#define NA 512
#define MROW (NB*NA)      // 4096 anchor rows total
#define NQKV (3*DM)       // 2304

typedef __attribute__((ext_vector_type(4))) float f32x4;
typedef __attribute__((ext_vector_type(8))) short s16x8;

static __device__ __forceinline__ unsigned short f2bf(float x) {
  unsigned int u = __float_as_uint(x);
  u += 0x7fffu + ((u >> 16) & 1u);          // RNE
  return (unsigned short)(u >> 16);
}
static __device__ __forceinline__ float bf2f(unsigned short h) {
  return __uint_as_float(((unsigned int)h) << 16);
}
static __device__ __forceinline__ void split2(float x, unsigned short& hi, unsigned short& lo) {
  hi = f2bf(x);
  lo = f2bf(x - bf2f(hi));                  // exact residual in fp32
}

static __device__ __forceinline__ void gld_lds16(const void* g, void* l) {
  __builtin_amdgcn_global_load_lds(
      (const __attribute__((address_space(1))) unsigned int*)g,
      (__attribute__((address_space(3))) unsigned int*)l, 16, 0, 0);
}

// ---------------- fast zero-fill of the output ----------------
__global__ __launch_bounds__(256) void fill_zero(f32x4* __restrict__ p, int n4) {
  const f32x4 z = {0.f, 0.f, 0.f, 0.f};
  int i = blockIdx.x * 256 + threadIdx.x;
  const int stride = gridDim.x * 256;
  for (; i < n4; i += stride) __builtin_nontemporal_store(z, p + i);
}

// ---------------- weights -> bf16 hi/lo split ----------------
__global__ __launch_bounds__(256) void prep_weights(
    const float* __restrict__ wq, const float* __restrict__ wk,
    const float* __restrict__ wv, const float* __restrict__ wo,
    unsigned short* __restrict__ w1h, unsigned short* __restrict__ w1l,
    unsigned short* __restrict__ woh, unsigned short* __restrict__ wol)
{
  int i = blockIdx.x * 256 + threadIdx.x;
  const int T1 = NQKV * DM;
  const int TW = DM * DM;
  if (i < T1) {
    float v = (i < TW) ? wq[i] : (i < 2*TW) ? wk[i - TW] : wv[i - 2*TW];
    unsigned short h, l; split2(v, h, l);
    w1h[i] = h; w1l[i] = l;
  } else if (i < T1 + TW) {
    int j = i - T1;
    unsigned short h, l; split2(wo[j], h, l);
    woh[j] = h; wol[j] = l;
  }
}

// ---------------- gather anchors + LayerNorm -> x hi/lo ----------------
__global__ __launch_bounds__(256) void gather_ln(
    const float* __restrict__ hs, const int* __restrict__ anc,
    const float* __restrict__ gam, const float* __restrict__ bet,
    unsigned short* __restrict__ xh, unsigned short* __restrict__ xl)
{
  int r = blockIdx.x;                 // 0..4095  (b,a)
  int b = r >> 9, a = r & (NA - 1);
  int idx = anc[b * NA + a];
  const float* src = hs + ((size_t)b * SEQ + idx) * DM;
  int t = threadIdx.x;
  float e0 = src[t], e1 = src[t + 256], e2 = src[t + 512];
  float s = e0 + e1 + e2;
  float ss = e0*e0 + e1*e1 + e2*e2;
  #pragma unroll
  for (int o = 1; o < 64; o <<= 1) { s += __shfl_xor(s, o); ss += __shfl_xor(ss, o); }
  __shared__ float red[8];
  int w = t >> 6, lane = t & 63;
  if (lane == 0) { red[w] = s; red[4 + w] = ss; }
  __syncthreads();
  s  = red[0] + red[1] + red[2] + red[3];
  ss = red[4] + red[5] + red[6] + red[7];
  float mu = s * (1.f / DM);
  float var = ss * (1.f / DM) - mu * mu;   // biased, matches jnp.var
  float rstd = rsqrtf(var + 1e-5f);
  size_t base = (size_t)r * DM;
  #pragma unroll
  for (int p = 0; p < 3; ++p) {
    int c = t + p * 256;
    float e = (p == 0) ? e0 : (p == 1) ? e1 : e2;
    float y = (e - mu) * rstd * gam[c] + bet[c];
    unsigned short h, l; split2(y, h, l);
    xh[base + c] = h; xl[base + c] = l;
  }
}

// ---------------- 128x128 split-bf16 NT GEMM (A[M][K], B[N][K]) ----------------
// EPI=1: QKV epilogue; EPI=2: out-proj epilogue with scatter.
template<int EPI>
__global__ __launch_bounds__(256, 2) void gemm128(
    const unsigned short* __restrict__ Ah, const unsigned short* __restrict__ Al,
    const unsigned short* __restrict__ Bh, const unsigned short* __restrict__ Bl,
    const float* __restrict__ biasq, const float* __restrict__ biask, const float* __restrict__ biasv,
    unsigned short* __restrict__ qh, unsigned short* __restrict__ ql,
    unsigned short* __restrict__ kh, unsigned short* __restrict__ kl,
    unsigned short* __restrict__ vh, unsigned short* __restrict__ vl,
    const float* __restrict__ biaso, const int* __restrict__ anc,
    float* __restrict__ outp)
{
  __shared__ unsigned short sAh[128 * 32], sAl[128 * 32], sBh[128 * 32], sBl[128 * 32];
  const int tid = threadIdx.x, lane = tid & 63, w = tid >> 6;
  const int wr = w >> 1, wc = w & 1;
  // bijective XCD swizzle (nwg % 8 == 0 for both launches): consecutive work
  // items within an XCD share the A row-panel -> L2 locality.
  const unsigned int nwg = gridDim.x * gridDim.y;
  const unsigned int orig = blockIdx.y * gridDim.x + blockIdx.x;
  const unsigned int wg = (orig & 7) * (nwg >> 3) + (orig >> 3);
  const int m0 = (int)(wg / gridDim.x) * 128, n0 = (int)(wg % gridDim.x) * 128;
  const int rsel = lane & 15, kg = lane >> 4;
  f32x4 acc[4][4] = {};

  for (int k0 = 0; k0 < DM; k0 += 32) {
    __syncthreads();
    #pragma unroll
    for (int c = 0; c < 2; ++c) {
      const int gg = w * 128 + c * 64;           // wave-uniform granule base
      const int g = gg + lane;
      const int row = g >> 2, slot = g & 3;
      const int kk = k0 + ((slot ^ ((row >> 1) & 3)) << 3);
      const size_t aoff = (size_t)(m0 + row) * DM + kk;
      const size_t boff = (size_t)(n0 + row) * DM + kk;
      gld_lds16(Ah + aoff, sAh + gg * 8);
      gld_lds16(Al + aoff, sAl + gg * 8);
      gld_lds16(Bh + boff, sBh + gg * 8);
      gld_lds16(Bl + boff, sBl + gg * 8);
    }
    __syncthreads();
    s16x8 afh[4], afl[4], bfh[4], bfl[4];
    #pragma unroll
    for (int i = 0; i < 4; ++i) {
      const int row = wr * 64 + i * 16 + rsel;
      const int aoff = row * 32 + ((kg ^ ((row >> 1) & 3)) << 3);
      afh[i] = *reinterpret_cast<const s16x8*>(sAh + aoff);
      afl[i] = *reinterpret_cast<const s16x8*>(sAl + aoff);
      const int col = wc * 64 + i * 16 + rsel;
      const int boff2 = col * 32 + ((kg ^ ((col >> 1) & 3)) << 3);
      bfh[i] = *reinterpret_cast<const s16x8*>(sBh + boff2);
      bfl[i] = *reinterpret_cast<const s16x8*>(sBl + boff2);
    }
    #pragma unroll
    for (int i = 0; i < 4; ++i)
      #pragma unroll
      for (int j = 0; j < 4; ++j) {
        acc[i][j] = __builtin_amdgcn_mfma_f32_16x16x32_bf16(afh[i], bfh[j], acc[i][j], 0, 0, 0);
        acc[i][j] = __builtin_amdgcn_mfma_f32_16x16x32_bf16(afh[i], bfl[j], acc[i][j], 0, 0, 0);
        acc[i][j] = __builtin_amdgcn_mfma_f32_16x16x32_bf16(afl[i], bfh[j], acc[i][j], 0, 0, 0);
      }
  }

  #pragma unroll
  for (int i = 0; i < 4; ++i)
    #pragma unroll
    for (int j = 0; j < 4; ++j)
      #pragma unroll
      for (int r = 0; r < 4; ++r) {
        const int row = m0 + wr * 64 + i * 16 + kg * 4 + r;   // C/D: row=(l>>4)*4+reg
        const int col = n0 + wc * 64 + j * 16 + rsel;          //      col=l&15
        const float v = acc[i][j][r];
        const int b = row >> 9, a = row & (NA - 1);
        if (EPI == 1) {
          const int sec = (col >= 2 * DM) ? 2 : (col >= DM ? 1 : 0);
          const int f = col - sec * DM;
          const int hh = f / HDIM, d = f - hh * HDIM;
          const float* bp = (sec == 0) ? biasq : (sec == 1) ? biask : biasv;
          const float val = v + bp[f];
          unsigned short hi, lo; split2(val, hi, lo);
          const int bhh = b * NHEAD + hh;
          if (sec == 0)      { const size_t o = ((size_t)bhh * NA + a) * HDIM + d; qh[o] = hi; ql[o] = lo; }
          else if (sec == 1) { const size_t o = ((size_t)bhh * NA + a) * HDIM + d; kh[o] = hi; kl[o] = lo; }
          else               { const size_t o = ((size_t)bhh * HDIM + d) * NA + a; vh[o] = hi; vl[o] = lo; } // V^T
        } else {
          const int sidx = anc[b * NA + a];
          outp[((size_t)b * SEQ + sidx) * DM + col] = v + biaso[col];
        }
      }
}

// ---------------- fused attention: 512 threads / 8 waves per (b,h,64-row Q tile) ----------
// Waves split QK^T by column-half, softmax by row, PV by output-dim half.
// LDS 128KiB -> 1 block/CU, but 8 waves => 2 waves/SIMD (2x the old latency hiding).
__global__ __launch_bounds__(512, 1) void attn_fused(
    const unsigned short* __restrict__ qh, const unsigned short* __restrict__ ql,
    const unsigned short* __restrict__ kh, const unsigned short* __restrict__ kl,
    const unsigned short* __restrict__ vh, const unsigned short* __restrict__ vl,
    unsigned short* __restrict__ oh, unsigned short* __restrict__ ol)
{
  __shared__ unsigned int S[64 * 512];   // fp32 scores, then packed P (hi<<16|lo). 128 KiB
  __shared__ float rsum_lds[64];
  const int blk = blockIdx.x;
  const int qt = blk & 7, bh = blk >> 3;
  const int b = bh >> 3, h = bh & 7;
  const int tid = threadIdx.x, lane = tid & 63, w = tid >> 6;
  const int rt = w & 3;                  // row-tile (16 rows)
  const int ch = w >> 2;                 // half selector
  const int rsel = lane & 15, kg = lane >> 4;
  const int q0 = qt * 64;

  // Q fragments for this wave's 16 rows (duplicated across the two halves; L1-hit)
  s16x8 qfh[3], qfl[3];
  {
    const size_t qrow = (size_t)bh * NA + q0 + rt * 16 + rsel;
    const unsigned short* qp  = qh + qrow * HDIM + kg * 8;
    const unsigned short* qp2 = ql + qrow * HDIM + kg * 8;
    #pragma unroll
    for (int kc = 0; kc < 3; ++kc) {
      qfh[kc] = *reinterpret_cast<const s16x8*>(qp  + kc * 32);
      qfl[kc] = *reinterpret_cast<const s16x8*>(qp2 + kc * 32);
    }
  }
  const float scale = 0.10206207261596575f;  // 1/sqrt(96)
  const unsigned short* kb_h = kh + (size_t)bh * NA * HDIM;
  const unsigned short* kb_l = kl + (size_t)bh * NA * HDIM;

  // S = Q K^T * scale ; wave (rt,ch) computes rows rt*16.., cts [ch*16, ch*16+16)
  for (int ct2 = 0; ct2 < 16; ++ct2) {
    const int ct = ch * 16 + ct2;
    f32x4 acc = {0.f, 0.f, 0.f, 0.f};
    const unsigned short* kp  = kb_h + (size_t)(ct * 16 + rsel) * HDIM + kg * 8;
    const unsigned short* kp2 = kb_l + (size_t)(ct * 16 + rsel) * HDIM + kg * 8;
    #pragma unroll
    for (int kc = 0; kc < 3; ++kc) {
      s16x8 kfh = *reinterpret_cast<const s16x8*>(kp  + kc * 32);
      s16x8 kfl = *reinterpret_cast<const s16x8*>(kp2 + kc * 32);
      __builtin_amdgcn_s_setprio(1);
      acc = __builtin_amdgcn_mfma_f32_16x16x32_bf16(qfh[kc], kfh, acc, 0, 0, 0);
      acc = __builtin_amdgcn_mfma_f32_16x16x32_bf16(qfh[kc], kfl, acc, 0, 0, 0);
      acc = __builtin_amdgcn_mfma_f32_16x16x32_bf16(qfl[kc], kfh, acc, 0, 0, 0);
      __builtin_amdgcn_s_setprio(0);
    }
    #pragma unroll
    for (int r = 0; r < 4; ++r) {
      int row = rt * 16 + kg * 4 + r;
      int col = ct * 16 + rsel;
      S[row * 512 + (col ^ ((row & 7) << 2))] = __float_as_uint(acc[r] * scale);
    }
  }
  __syncthreads();

  // softmax: 8 lanes per row (wave w owns rows w*8..w*8+7), 64 cols per lane
  {
    const int row = w * 8 + (lane >> 3);
    const int sub = lane & 7;
    const int srow = (row & 7) << 2;
    unsigned int* rowp = &S[row * 512];
    float mx = -3.0e38f;
    #pragma unroll 8
    for (int i = 0; i < 16; ++i) {
      int c = sub * 64 + i * 4;
      uint4 u = *reinterpret_cast<const uint4*>(rowp + (c ^ srow));
      mx = fmaxf(mx, fmaxf(fmaxf(__uint_as_float(u.x), __uint_as_float(u.y)),
                           fmaxf(__uint_as_float(u.z), __uint_as_float(u.w))));
    }
    mx = fmaxf(mx, __shfl_xor(mx, 1));
    mx = fmaxf(mx, __shfl_xor(mx, 2));
    mx = fmaxf(mx, __shfl_xor(mx, 4));
    float sum = 0.f;
    #pragma unroll 8
    for (int i = 0; i < 16; ++i) {
      int c = sub * 64 + i * 4;
      uint4 u = *reinterpret_cast<const uint4*>(rowp + (c ^ srow));
      float p0 = __expf(__uint_as_float(u.x) - mx);
      float p1 = __expf(__uint_as_float(u.y) - mx);
      float p2 = __expf(__uint_as_float(u.z) - mx);
      float p3 = __expf(__uint_as_float(u.w) - mx);
      sum += p0 + p1 + p2 + p3;
      unsigned short h0,l0,h1,l1,h2,l2,h3,l3;
      split2(p0,h0,l0); split2(p1,h1,l1); split2(p2,h2,l2); split2(p3,h3,l3);
      uint4 pk;
      pk.x = ((unsigned)h0 << 16) | l0;
      pk.y = ((unsigned)h1 << 16) | l1;
      pk.z = ((unsigned)h2 << 16) | l2;
      pk.w = ((unsigned)h3 << 16) | l3;
      *reinterpret_cast<uint4*>(rowp + (c ^ srow)) = pk;
    }
    sum += __shfl_xor(sum, 1);
    sum += __shfl_xor(sum, 2);
    sum += __shfl_xor(sum, 4);
    if (sub == 0) rsum_lds[row] = 1.f / sum;
  }
  __syncthreads();

  // O = P V : wave (rt,ch) computes rows rt*16.., output tiles nt = ch*3 .. ch*3+2
  const unsigned short* vb_h = vh + (size_t)bh * HDIM * NA;
  const unsigned short* vb_l = vl + (size_t)bh * HDIM * NA;
  const int ntbase = ch * 3;
  f32x4 acc[3] = {};
  {
    const int row = rt * 16 + rsel;
    const int srow = (row & 7) << 2;
    const unsigned int* rowp = &S[row * 512];
    for (int kc = 0; kc < 16; ++kc) {
      int c = kc * 32 + kg * 8;
      uint4 ua = *reinterpret_cast<const uint4*>(rowp + ((c) ^ srow));
      uint4 ub = *reinterpret_cast<const uint4*>(rowp + ((c + 4) ^ srow));
      s16x8 ph, pl;
      ph[0] = (short)(ua.x >> 16); pl[0] = (short)(ua.x & 0xffff);
      ph[1] = (short)(ua.y >> 16); pl[1] = (short)(ua.y & 0xffff);
      ph[2] = (short)(ua.z >> 16); pl[2] = (short)(ua.z & 0xffff);
      ph[3] = (short)(ua.w >> 16); pl[3] = (short)(ua.w & 0xffff);
      ph[4] = (short)(ub.x >> 16); pl[4] = (short)(ub.x & 0xffff);
      ph[5] = (short)(ub.y >> 16); pl[5] = (short)(ub.y & 0xffff);
      ph[6] = (short)(ub.z >> 16); pl[6] = (short)(ub.z & 0xffff);
      ph[7] = (short)(ub.w >> 16); pl[7] = (short)(ub.w & 0xffff);
      #pragma unroll
      for (int j = 0; j < 3; ++j) {
        const int nt = ntbase + j;
        const unsigned short* vp  = vb_h + (size_t)(nt * 16 + rsel) * NA + c;
        const unsigned short* vp2 = vb_l + (size_t)(nt * 16 + rsel) * NA + c;
        s16x8 vfh = *reinterpret_cast<const s16x8*>(vp);
        s16x8 vfl = *reinterpret_cast<const s16x8*>(vp2);
        __builtin_amdgcn_s_setprio(1);
        acc[j] = __builtin_amdgcn_mfma_f32_16x16x32_bf16(ph, vfh, acc[j], 0, 0, 0);
        acc[j] = __builtin_amdgcn_mfma_f32_16x16x32_bf16(ph, vfl, acc[j], 0, 0, 0);
        acc[j] = __builtin_amdgcn_mfma_f32_16x16x32_bf16(pl, vfh, acc[j], 0, 0, 0);
        __builtin_amdgcn_s_setprio(0);
      }
    }
  }

  #pragma unroll
  for (int r = 0; r < 4; ++r) {
    const float rinv = rsum_lds[rt * 16 + kg * 4 + r];
    const int rowg = b * NA + q0 + rt * 16 + kg * 4 + r;
    #pragma unroll
    for (int j = 0; j < 3; ++j) {
      const int nt = ntbase + j;
      float val = acc[j][r] * rinv;
      unsigned short hi, lo; split2(val, hi, lo);
      size_t o = (size_t)rowg * DM + h * HDIM + nt * 16 + rsel;
      oh[o] = hi; ol[o] = lo;
    }
  }
}

extern "C" void kernel_launch(void* const* d_in, const int* in_sizes, int n_in,
                              void* d_out, int out_size, void* d_ws, size_t ws_size,
                              hipStream_t stream)
{
  const float* hs   = (const float*)d_in[0];
  const int*   anc  = (const int*)d_in[1];
  const float* ln_g = (const float*)d_in[2];
  const float* ln_b = (const float*)d_in[3];
  const float* wq = (const float*)d_in[4];
  const float* bq = (const float*)d_in[5];
  const float* wk = (const float*)d_in[6];
  const float* bk = (const float*)d_in[7];
  const float* wv = (const float*)d_in[8];
  const float* bv = (const float*)d_in[9];
  const float* wo = (const float*)d_in[10];
  const float* bo = (const float*)d_in[11];
  float* outp = (float*)d_out;

  char* ws = (char*)d_ws;
  size_t off = 0;
  auto take = [&](size_t bytes) { char* p = ws + off; off += (bytes + 255) & ~(size_t)255; return p; };
  unsigned short* xh  = (unsigned short*)take((size_t)MROW * DM * 2);
  unsigned short* xl  = (unsigned short*)take((size_t)MROW * DM * 2);
  unsigned short* w1h = (unsigned short*)take((size_t)NQKV * DM * 2);
  unsigned short* w1l = (unsigned short*)take((size_t)NQKV * DM * 2);
  unsigned short* woh = (unsigned short*)take((size_t)DM * DM * 2);
  unsigned short* wol = (unsigned short*)take((size_t)DM * DM * 2);
  const size_t qkvsz = (size_t)NB * NHEAD * NA * HDIM * 2;
  unsigned short* qhb = (unsigned short*)take(qkvsz);
  unsigned short* qlb = (unsigned short*)take(qkvsz);
  unsigned short* khb = (unsigned short*)take(qkvsz);
  unsigned short* klb = (unsigned short*)take(qkvsz);
  unsigned short* vhb = (unsigned short*)take(qkvsz);
  unsigned short* vlb = (unsigned short*)take(qkvsz);
  unsigned short* ohb = (unsigned short*)take((size_t)MROW * DM * 2);
  unsigned short* olb = (unsigned short*)take((size_t)MROW * DM * 2);

  fill_zero<<<2048, 256, 0, stream>>>((f32x4*)outp, out_size / 4);
  prep_weights<<<(NQKV * DM + DM * DM + 255) / 256, 256, 0, stream>>>(
      wq, wk, wv, wo, w1h, w1l, woh, wol);
  gather_ln<<<MROW, 256, 0, stream>>>(hs, anc, ln_g, ln_b, xh, xl);
  gemm128<1><<<dim3(NQKV / 128, MROW / 128), 256, 0, stream>>>(
      xh, xl, w1h, w1l, bq, bk, bv, qhb, qlb, khb, klb, vhb, vlb,
      nullptr, nullptr, nullptr);
  attn_fused<<<NB * NHEAD * 8, 512, 0, stream>>>(qhb, qlb, khb, klb, vhb, vlb, ohb, olb);
  gemm128<2><<<dim3(DM / 128, MROW / 128), 256, 0, stream>>>(
      ohb, olb, woh, wol, nullptr, nullptr, nullptr,
      nullptr, nullptr, nullptr, nullptr, nullptr, nullptr, bo, anc, outp);
}

// Round 4
// 236.423 us; speedup vs baseline: 1.1663x; 1.0863x over previous
//
#include <hip/hip_runtime.h>

#define DM 768
#define NHEAD 8
#define HDIM 96
#define NB 8
#define SEQ 8192
#define NA 512
#define MROW (NB*NA)      // 4096 anchor rows total
#define NQKV (3*DM)       // 2304
#define QBLK 32

typedef __attribute__((ext_vector_type(4))) float f32x4;
typedef __attribute__((ext_vector_type(8))) short s16x8;

static __device__ __forceinline__ unsigned short f2bf(float x) {
  unsigned int u = __float_as_uint(x);
  u += 0x7fffu + ((u >> 16) & 1u);          // RNE
  return (unsigned short)(u >> 16);
}
static __device__ __forceinline__ float bf2f(unsigned short h) {
  return __uint_as_float(((unsigned int)h) << 16);
}
static __device__ __forceinline__ void split2(float x, unsigned short& hi, unsigned short& lo) {
  hi = f2bf(x);
  lo = f2bf(x - bf2f(hi));                  // exact residual in fp32
}

static __device__ __forceinline__ void gld_lds16(const void* g, void* l) {
  __builtin_amdgcn_global_load_lds(
      (const __attribute__((address_space(1))) unsigned int*)g,
      (__attribute__((address_space(3))) unsigned int*)l, 16, 0, 0);
}

// ---------------- prologue: fill(out) + weight-split + gather+LN, one dispatch ----------
// blocks [0,4096): gather+LN ; [4096,6400): weight split (float4) ; [6400,8448): fill.
__global__ __launch_bounds__(256) void prologue(
    const float* __restrict__ hs, const int* __restrict__ anc,
    const float* __restrict__ gam, const float* __restrict__ bet,
    const float* __restrict__ wq, const float* __restrict__ wk,
    const float* __restrict__ wv, const float* __restrict__ wo,
    unsigned short* __restrict__ xh, unsigned short* __restrict__ xl,
    unsigned short* __restrict__ w1h, unsigned short* __restrict__ w1l,
    unsigned short* __restrict__ woh, unsigned short* __restrict__ wol,
    f32x4* __restrict__ outp, int n4)
{
  __shared__ float red[8];
  const int bid = blockIdx.x;
  const int t = threadIdx.x;
  if (bid < MROW) {
    // ---- gather + LayerNorm ----
    int r = bid;
    int b = r >> 9, a = r & (NA - 1);
    int idx = anc[b * NA + a];
    const float* src = hs + ((size_t)b * SEQ + idx) * DM;
    float e0 = src[t], e1 = src[t + 256], e2 = src[t + 512];
    float s = e0 + e1 + e2;
    float ss = e0*e0 + e1*e1 + e2*e2;
    #pragma unroll
    for (int o = 1; o < 64; o <<= 1) { s += __shfl_xor(s, o); ss += __shfl_xor(ss, o); }
    int w = t >> 6, lane = t & 63;
    if (lane == 0) { red[w] = s; red[4 + w] = ss; }
    __syncthreads();
    s  = red[0] + red[1] + red[2] + red[3];
    ss = red[4] + red[5] + red[6] + red[7];
    float mu = s * (1.f / DM);
    float var = ss * (1.f / DM) - mu * mu;   // biased, matches jnp.var
    float rstd = rsqrtf(var + 1e-5f);
    size_t base = (size_t)r * DM;
    #pragma unroll
    for (int p = 0; p < 3; ++p) {
      int c = t + p * 256;
      float e = (p == 0) ? e0 : (p == 1) ? e1 : e2;
      float y = (e - mu) * rstd * gam[c] + bet[c];
      unsigned short h, l; split2(y, h, l);
      xh[base + c] = h; xl[base + c] = l;
    }
  } else if (bid < MROW + 2304) {
    // ---- weight hi/lo split, float4 ----
    const int i = (bid - MROW) * 256 + t;    // float4 index
    const int T1_4 = (NQKV * DM) / 4;        // 442368
    const int TW_4 = (DM * DM) / 4;          // 147456
    float4 v;
    unsigned short* dh; unsigned short* dl; int e4;
    if (i < T1_4) {
      v = (i < TW_4) ? reinterpret_cast<const float4*>(wq)[i]
        : (i < 2*TW_4) ? reinterpret_cast<const float4*>(wk)[i - TW_4]
                       : reinterpret_cast<const float4*>(wv)[i - 2*TW_4];
      dh = w1h; dl = w1l; e4 = i;
    } else {
      int j = i - T1_4;
      v = reinterpret_cast<const float4*>(wo)[j];
      dh = woh; dl = wol; e4 = j;
    }
    unsigned short h0,l0,h1,l1,h2,l2,h3,l3;
    split2(v.x,h0,l0); split2(v.y,h1,l1); split2(v.z,h2,l2); split2(v.w,h3,l3);
    uint2 ph, pl;
    ph.x = (unsigned)h0 | ((unsigned)h1 << 16); ph.y = (unsigned)h2 | ((unsigned)h3 << 16);
    pl.x = (unsigned)l0 | ((unsigned)l1 << 16); pl.y = (unsigned)l2 | ((unsigned)l3 << 16);
    reinterpret_cast<uint2*>(dh)[e4] = ph;
    reinterpret_cast<uint2*>(dl)[e4] = pl;
  } else {
    // ---- zero-fill output ----
    const f32x4 z = {0.f, 0.f, 0.f, 0.f};
    int i = (bid - MROW - 2304) * 256 + t;
    for (; i < n4; i += 2048 * 256) __builtin_nontemporal_store(z, outp + i);
  }
}

// ---------------- 128x128 split-bf16 NT GEMM (A[M][K], B[N][K]) ----------------
// EPI=1: QKV epilogue; EPI=2: out-proj epilogue with scatter.
template<int EPI>
__global__ __launch_bounds__(256, 2) void gemm128(
    const unsigned short* __restrict__ Ah, const unsigned short* __restrict__ Al,
    const unsigned short* __restrict__ Bh, const unsigned short* __restrict__ Bl,
    const float* __restrict__ biasq, const float* __restrict__ biask, const float* __restrict__ biasv,
    unsigned short* __restrict__ qh, unsigned short* __restrict__ ql,
    unsigned short* __restrict__ kh, unsigned short* __restrict__ kl,
    unsigned short* __restrict__ vh, unsigned short* __restrict__ vl,
    const float* __restrict__ biaso, const int* __restrict__ anc,
    float* __restrict__ outp)
{
  __shared__ unsigned short sAh[128 * 32], sAl[128 * 32], sBh[128 * 32], sBl[128 * 32];
  const int tid = threadIdx.x, lane = tid & 63, w = tid >> 6;
  const int wr = w >> 1, wc = w & 1;
  // bijective XCD swizzle (nwg % 8 == 0 for both launches)
  const unsigned int nwg = gridDim.x * gridDim.y;
  const unsigned int orig = blockIdx.y * gridDim.x + blockIdx.x;
  const unsigned int wg = (orig & 7) * (nwg >> 3) + (orig >> 3);
  const int m0 = (int)(wg / gridDim.x) * 128, n0 = (int)(wg % gridDim.x) * 128;
  const int rsel = lane & 15, kg = lane >> 4;
  f32x4 acc[4][4] = {};

  for (int k0 = 0; k0 < DM; k0 += 32) {
    __syncthreads();
    #pragma unroll
    for (int c = 0; c < 2; ++c) {
      const int gg = w * 128 + c * 64;           // wave-uniform granule base
      const int g = gg + lane;
      const int row = g >> 2, slot = g & 3;
      const int kk = k0 + ((slot ^ ((row >> 1) & 3)) << 3);
      const size_t aoff = (size_t)(m0 + row) * DM + kk;
      const size_t boff = (size_t)(n0 + row) * DM + kk;
      gld_lds16(Ah + aoff, sAh + gg * 8);
      gld_lds16(Al + aoff, sAl + gg * 8);
      gld_lds16(Bh + boff, sBh + gg * 8);
      gld_lds16(Bl + boff, sBl + gg * 8);
    }
    __syncthreads();
    s16x8 afh[4], afl[4], bfh[4], bfl[4];
    #pragma unroll
    for (int i = 0; i < 4; ++i) {
      const int row = wr * 64 + i * 16 + rsel;
      const int aoff = row * 32 + ((kg ^ ((row >> 1) & 3)) << 3);
      afh[i] = *reinterpret_cast<const s16x8*>(sAh + aoff);
      afl[i] = *reinterpret_cast<const s16x8*>(sAl + aoff);
      const int col = wc * 64 + i * 16 + rsel;
      const int boff2 = col * 32 + ((kg ^ ((col >> 1) & 3)) << 3);
      bfh[i] = *reinterpret_cast<const s16x8*>(sBh + boff2);
      bfl[i] = *reinterpret_cast<const s16x8*>(sBl + boff2);
    }
    #pragma unroll
    for (int i = 0; i < 4; ++i)
      #pragma unroll
      for (int j = 0; j < 4; ++j) {
        acc[i][j] = __builtin_amdgcn_mfma_f32_16x16x32_bf16(afh[i], bfh[j], acc[i][j], 0, 0, 0);
        acc[i][j] = __builtin_amdgcn_mfma_f32_16x16x32_bf16(afh[i], bfl[j], acc[i][j], 0, 0, 0);
        acc[i][j] = __builtin_amdgcn_mfma_f32_16x16x32_bf16(afl[i], bfh[j], acc[i][j], 0, 0, 0);
      }
  }

  #pragma unroll
  for (int i = 0; i < 4; ++i)
    #pragma unroll
    for (int j = 0; j < 4; ++j)
      #pragma unroll
      for (int r = 0; r < 4; ++r) {
        const int row = m0 + wr * 64 + i * 16 + kg * 4 + r;   // C/D: row=(l>>4)*4+reg
        const int col = n0 + wc * 64 + j * 16 + rsel;          //      col=l&15
        const float v = acc[i][j][r];
        const int b = row >> 9, a = row & (NA - 1);
        if (EPI == 1) {
          const int sec = (col >= 2 * DM) ? 2 : (col >= DM ? 1 : 0);
          const int f = col - sec * DM;
          const int hh = f / HDIM, d = f - hh * HDIM;
          const float* bp = (sec == 0) ? biasq : (sec == 1) ? biask : biasv;
          const float val = v + bp[f];
          unsigned short hi, lo; split2(val, hi, lo);
          const int bhh = b * NHEAD + hh;
          if (sec == 0)      { const size_t o = ((size_t)bhh * NA + a) * HDIM + d; qh[o] = hi; ql[o] = lo; }
          else if (sec == 1) { const size_t o = ((size_t)bhh * NA + a) * HDIM + d; kh[o] = hi; kl[o] = lo; }
          else               { const size_t o = ((size_t)bhh * HDIM + d) * NA + a; vh[o] = hi; vl[o] = lo; } // V^T
        } else {
          const int sidx = anc[b * NA + a];
          outp[((size_t)b * SEQ + sidx) * DM + col] = v + biaso[col];
        }
      }
}

// ---------------- fused attention: 32-row Q tiles, 64 KB LDS, 2 blocks/CU ----------
// 8 waves: QK^T split (rt x 4 ct-quarters); softmax 4 rows/wave (interleaved cols,
// bank-floor); PV 12 (rt,nt) tasks round-robined.
__global__ __launch_bounds__(512, 4) void attn_fused(
    const unsigned short* __restrict__ qh, const unsigned short* __restrict__ ql,
    const unsigned short* __restrict__ kh, const unsigned short* __restrict__ kl,
    const unsigned short* __restrict__ vh, const unsigned short* __restrict__ vl,
    unsigned short* __restrict__ oh, unsigned short* __restrict__ ol)
{
  __shared__ unsigned int S[QBLK * 512];   // fp32 scores -> packed P. 64 KiB
  __shared__ float rsum_lds[QBLK];
  const int blk = blockIdx.x;
  const int qt = blk & 15, bh = blk >> 4;
  const int b = bh >> 3, h = bh & 7;
  const int tid = threadIdx.x, lane = tid & 63, w = tid >> 6;
  const int rt = w & 1, ctq = w >> 1;    // QK^T: rows rt*16.., ct in [ctq*8, ctq*8+8)
  const int rsel = lane & 15, kg = lane >> 4;
  const int q0 = qt * QBLK;

  // Q fragments for this wave's 16 rows
  s16x8 qfh[3], qfl[3];
  {
    const size_t qrow = (size_t)bh * NA + q0 + rt * 16 + rsel;
    const unsigned short* qp  = qh + qrow * HDIM + kg * 8;
    const unsigned short* qp2 = ql + qrow * HDIM + kg * 8;
    #pragma unroll
    for (int kc = 0; kc < 3; ++kc) {
      qfh[kc] = *reinterpret_cast<const s16x8*>(qp  + kc * 32);
      qfl[kc] = *reinterpret_cast<const s16x8*>(qp2 + kc * 32);
    }
  }
  const float scale = 0.10206207261596575f;  // 1/sqrt(96)
  const unsigned short* kb_h = kh + (size_t)bh * NA * HDIM;
  const unsigned short* kb_l = kl + (size_t)bh * NA * HDIM;

  for (int ct2 = 0; ct2 < 8; ++ct2) {
    const int ct = ctq * 8 + ct2;
    f32x4 acc = {0.f, 0.f, 0.f, 0.f};
    const unsigned short* kp  = kb_h + (size_t)(ct * 16 + rsel) * HDIM + kg * 8;
    const unsigned short* kp2 = kb_l + (size_t)(ct * 16 + rsel) * HDIM + kg * 8;
    #pragma unroll
    for (int kc = 0; kc < 3; ++kc) {
      s16x8 kfh = *reinterpret_cast<const s16x8*>(kp  + kc * 32);
      s16x8 kfl = *reinterpret_cast<const s16x8*>(kp2 + kc * 32);
      __builtin_amdgcn_s_setprio(1);
      acc = __builtin_amdgcn_mfma_f32_16x16x32_bf16(qfh[kc], kfh, acc, 0, 0, 0);
      acc = __builtin_amdgcn_mfma_f32_16x16x32_bf16(qfh[kc], kfl, acc, 0, 0, 0);
      acc = __builtin_amdgcn_mfma_f32_16x16x32_bf16(qfl[kc], kfh, acc, 0, 0, 0);
      __builtin_amdgcn_s_setprio(0);
    }
    #pragma unroll
    for (int r = 0; r < 4; ++r) {
      int row = rt * 16 + kg * 4 + r;
      int col = ct * 16 + rsel;
      S[row * 512 + (col ^ ((row & 7) << 2))] = __float_as_uint(acc[r] * scale);
    }
  }
  __syncthreads();

  // softmax: wave w owns rows w*4..w*4+3; 16 lanes/row; interleaved cols (bank-floor)
  {
    const int row = w * 4 + (lane >> 4);
    const int sub = lane & 15;
    const int srow = (row & 7) << 2;
    unsigned int* rowp = &S[row * 512];
    float mx = -3.0e38f;
    #pragma unroll 8
    for (int i = 0; i < 8; ++i) {
      int c = sub * 4 + i * 64;
      uint4 u = *reinterpret_cast<const uint4*>(rowp + (c ^ srow));
      mx = fmaxf(mx, fmaxf(fmaxf(__uint_as_float(u.x), __uint_as_float(u.y)),
                           fmaxf(__uint_as_float(u.z), __uint_as_float(u.w))));
    }
    mx = fmaxf(mx, __shfl_xor(mx, 1));
    mx = fmaxf(mx, __shfl_xor(mx, 2));
    mx = fmaxf(mx, __shfl_xor(mx, 4));
    mx = fmaxf(mx, __shfl_xor(mx, 8));
    float sum = 0.f;
    #pragma unroll 8
    for (int i = 0; i < 8; ++i) {
      int c = sub * 4 + i * 64;
      uint4 u = *reinterpret_cast<const uint4*>(rowp + (c ^ srow));
      float p0 = __expf(__uint_as_float(u.x) - mx);
      float p1 = __expf(__uint_as_float(u.y) - mx);
      float p2 = __expf(__uint_as_float(u.z) - mx);
      float p3 = __expf(__uint_as_float(u.w) - mx);
      sum += p0 + p1 + p2 + p3;
      unsigned short h0,l0,h1,l1,h2,l2,h3,l3;
      split2(p0,h0,l0); split2(p1,h1,l1); split2(p2,h2,l2); split2(p3,h3,l3);
      uint4 pk;
      pk.x = ((unsigned)h0 << 16) | l0;
      pk.y = ((unsigned)h1 << 16) | l1;
      pk.z = ((unsigned)h2 << 16) | l2;
      pk.w = ((unsigned)h3 << 16) | l3;
      *reinterpret_cast<uint4*>(rowp + (c ^ srow)) = pk;
    }
    sum += __shfl_xor(sum, 1);
    sum += __shfl_xor(sum, 2);
    sum += __shfl_xor(sum, 4);
    sum += __shfl_xor(sum, 8);
    if (sub == 0) rsum_lds[row] = 1.f / sum;
  }
  __syncthreads();

  // O = P V : 12 tasks (rt2 in {0,1}) x (nt in [0,6)), round-robined over 8 waves
  const unsigned short* vb_h = vh + (size_t)bh * HDIM * NA;
  const unsigned short* vb_l = vl + (size_t)bh * HDIM * NA;
  for (int task = w; task < 12; task += 8) {
    const int nt = task % 6, rt2 = task / 6;
    f32x4 acc = {0.f, 0.f, 0.f, 0.f};
    const int row = rt2 * 16 + rsel;
    const int srow = (row & 7) << 2;
    const unsigned int* rowp = &S[row * 512];
    for (int kc = 0; kc < 16; ++kc) {
      int c = kc * 32 + kg * 8;
      uint4 ua = *reinterpret_cast<const uint4*>(rowp + ((c) ^ srow));
      uint4 ub = *reinterpret_cast<const uint4*>(rowp + ((c + 4) ^ srow));
      s16x8 ph, pl;
      ph[0] = (short)(ua.x >> 16); pl[0] = (short)(ua.x & 0xffff);
      ph[1] = (short)(ua.y >> 16); pl[1] = (short)(ua.y & 0xffff);
      ph[2] = (short)(ua.z >> 16); pl[2] = (short)(ua.z & 0xffff);
      ph[3] = (short)(ua.w >> 16); pl[3] = (short)(ua.w & 0xffff);
      ph[4] = (short)(ub.x >> 16); pl[4] = (short)(ub.x & 0xffff);
      ph[5] = (short)(ub.y >> 16); pl[5] = (short)(ub.y & 0xffff);
      ph[6] = (short)(ub.z >> 16); pl[6] = (short)(ub.z & 0xffff);
      ph[7] = (short)(ub.w >> 16); pl[7] = (short)(ub.w & 0xffff);
      const unsigned short* vp  = vb_h + (size_t)(nt * 16 + rsel) * NA + c;
      const unsigned short* vp2 = vb_l + (size_t)(nt * 16 + rsel) * NA + c;
      s16x8 vfh = *reinterpret_cast<const s16x8*>(vp);
      s16x8 vfl = *reinterpret_cast<const s16x8*>(vp2);
      __builtin_amdgcn_s_setprio(1);
      acc = __builtin_amdgcn_mfma_f32_16x16x32_bf16(ph, vfh, acc, 0, 0, 0);
      acc = __builtin_amdgcn_mfma_f32_16x16x32_bf16(ph, vfl, acc, 0, 0, 0);
      acc = __builtin_amdgcn_mfma_f32_16x16x32_bf16(pl, vfh, acc, 0, 0, 0);
      __builtin_amdgcn_s_setprio(0);
    }
    #pragma unroll
    for (int r = 0; r < 4; ++r) {
      const float rinv = rsum_lds[rt2 * 16 + kg * 4 + r];
      const int rowg = b * NA + q0 + rt2 * 16 + kg * 4 + r;
      float val = acc[r] * rinv;
      unsigned short hi, lo; split2(val, hi, lo);
      size_t o = (size_t)rowg * DM + h * HDIM + nt * 16 + rsel;
      oh[o] = hi; ol[o] = lo;
    }
  }
}

extern "C" void kernel_launch(void* const* d_in, const int* in_sizes, int n_in,
                              void* d_out, int out_size, void* d_ws, size_t ws_size,
                              hipStream_t stream)
{
  const float* hs   = (const float*)d_in[0];
  const int*   anc  = (const int*)d_in[1];
  const float* ln_g = (const float*)d_in[2];
  const float* ln_b = (const float*)d_in[3];
  const float* wq = (const float*)d_in[4];
  const float* bq = (const float*)d_in[5];
  const float* wk = (const float*)d_in[6];
  const float* bk = (const float*)d_in[7];
  const float* wv = (const float*)d_in[8];
  const float* bv = (const float*)d_in[9];
  const float* wo = (const float*)d_in[10];
  const float* bo = (const float*)d_in[11];
  float* outp = (float*)d_out;

  char* ws = (char*)d_ws;
  size_t off = 0;
  auto take = [&](size_t bytes) { char* p = ws + off; off += (bytes + 255) & ~(size_t)255; return p; };
  unsigned short* xh  = (unsigned short*)take((size_t)MROW * DM * 2);
  unsigned short* xl  = (unsigned short*)take((size_t)MROW * DM * 2);
  unsigned short* w1h = (unsigned short*)take((size_t)NQKV * DM * 2);
  unsigned short* w1l = (unsigned short*)take((size_t)NQKV * DM * 2);
  unsigned short* woh = (unsigned short*)take((size_t)DM * DM * 2);
  unsigned short* wol = (unsigned short*)take((size_t)DM * DM * 2);
  const size_t qkvsz = (size_t)NB * NHEAD * NA * HDIM * 2;
  unsigned short* qhb = (unsigned short*)take(qkvsz);
  unsigned short* qlb = (unsigned short*)take(qkvsz);
  unsigned short* khb = (unsigned short*)take(qkvsz);
  unsigned short* klb = (unsigned short*)take(qkvsz);
  unsigned short* vhb = (unsigned short*)take(qkvsz);
  unsigned short* vlb = (unsigned short*)take(qkvsz);
  unsigned short* ohb = (unsigned short*)take((size_t)MROW * DM * 2);
  unsigned short* olb = (unsigned short*)take((size_t)MROW * DM * 2);

  prologue<<<MROW + 2304 + 2048, 256, 0, stream>>>(
      hs, anc, ln_g, ln_b, wq, wk, wv, wo,
      xh, xl, w1h, w1l, woh, wol, (f32x4*)outp, out_size / 4);
  gemm128<1><<<dim3(NQKV / 128, MROW / 128), 256, 0, stream>>>(
      xh, xl, w1h, w1l, bq, bk, bv, qhb, qlb, khb, klb, vhb, vlb,
      nullptr, nullptr, nullptr);
  attn_fused<<<NB * NHEAD * (NA / QBLK), 512, 0, stream>>>(
      qhb, qlb, khb, klb, vhb, vlb, ohb, olb);
  gemm128<2><<<dim3(DM / 128, MROW / 128), 256, 0, stream>>>(
      ohb, olb, woh, wol, nullptr, nullptr, nullptr,
      nullptr, nullptr, nullptr, nullptr, nullptr, nullptr, bo, anc, outp);
}

// Round 5
// 179.236 us; speedup vs baseline: 1.5385x; 1.3191x over previous
//
#include <hip/hip_runtime.h>

#define DM 768
#define NHEAD 8
#define HDIM 96
#define NB 8
#define SEQ 8192
#define NA 512
#define MROW (NB*NA)      // 4096 anchor rows total
#define NQKV (3*DM)       // 2304
#define QBLK 32
#define FILLB 512         // fill blocks appended to gemm1's grid

typedef __attribute__((ext_vector_type(4))) float f32x4;
typedef __attribute__((ext_vector_type(8))) short s16x8;

static __device__ __forceinline__ unsigned short f2bf(float x) {
  unsigned int u = __float_as_uint(x);
  u += 0x7fffu + ((u >> 16) & 1u);          // RNE
  return (unsigned short)(u >> 16);
}
static __device__ __forceinline__ float bf2f(unsigned short h) {
  return __uint_as_float(((unsigned int)h) << 16);
}
static __device__ __forceinline__ void split2(float x, unsigned short& hi, unsigned short& lo) {
  hi = f2bf(x);
  lo = f2bf(x - bf2f(hi));                  // exact residual in fp32
}

static __device__ __forceinline__ void gld_lds16(const void* g, void* l) {
  __builtin_amdgcn_global_load_lds(
      (const __attribute__((address_space(1))) unsigned int*)g,
      (__attribute__((address_space(3))) unsigned int*)l, 16, 0, 0);
}

// ---------------- prologue: weight-split + gather+LN (fill moved into gemm1) ----------
__global__ __launch_bounds__(256) void prologue(
    const float* __restrict__ hs, const int* __restrict__ anc,
    const float* __restrict__ gam, const float* __restrict__ bet,
    const float* __restrict__ wq, const float* __restrict__ wk,
    const float* __restrict__ wv, const float* __restrict__ wo,
    unsigned short* __restrict__ xh, unsigned short* __restrict__ xl,
    unsigned short* __restrict__ w1h, unsigned short* __restrict__ w1l,
    unsigned short* __restrict__ woh, unsigned short* __restrict__ wol)
{
  __shared__ float red[8];
  const int bid = blockIdx.x;
  const int t = threadIdx.x;
  if (bid < MROW) {
    // ---- gather + LayerNorm ----
    int r = bid;
    int b = r >> 9, a = r & (NA - 1);
    int idx = anc[b * NA + a];
    const float* src = hs + ((size_t)b * SEQ + idx) * DM;
    float e0 = src[t], e1 = src[t + 256], e2 = src[t + 512];
    float s = e0 + e1 + e2;
    float ss = e0*e0 + e1*e1 + e2*e2;
    #pragma unroll
    for (int o = 1; o < 64; o <<= 1) { s += __shfl_xor(s, o); ss += __shfl_xor(ss, o); }
    int w = t >> 6, lane = t & 63;
    if (lane == 0) { red[w] = s; red[4 + w] = ss; }
    __syncthreads();
    s  = red[0] + red[1] + red[2] + red[3];
    ss = red[4] + red[5] + red[6] + red[7];
    float mu = s * (1.f / DM);
    float var = ss * (1.f / DM) - mu * mu;   // biased, matches jnp.var
    float rstd = rsqrtf(var + 1e-5f);
    size_t base = (size_t)r * DM;
    #pragma unroll
    for (int p = 0; p < 3; ++p) {
      int c = t + p * 256;
      float e = (p == 0) ? e0 : (p == 1) ? e1 : e2;
      float y = (e - mu) * rstd * gam[c] + bet[c];
      unsigned short h, l; split2(y, h, l);
      xh[base + c] = h; xl[base + c] = l;
    }
  } else {
    // ---- weight hi/lo split, float4 ----
    const int i = (bid - MROW) * 256 + t;    // float4 index
    const int T1_4 = (NQKV * DM) / 4;        // 442368
    const int TW_4 = (DM * DM) / 4;          // 147456
    float4 v;
    unsigned short* dh; unsigned short* dl; int e4;
    if (i < T1_4) {
      v = (i < TW_4) ? reinterpret_cast<const float4*>(wq)[i]
        : (i < 2*TW_4) ? reinterpret_cast<const float4*>(wk)[i - TW_4]
                       : reinterpret_cast<const float4*>(wv)[i - 2*TW_4];
      dh = w1h; dl = w1l; e4 = i;
    } else {
      int j = i - T1_4;
      v = reinterpret_cast<const float4*>(wo)[j];
      dh = woh; dl = wol; e4 = j;
    }
    unsigned short h0,l0,h1,l1,h2,l2,h3,l3;
    split2(v.x,h0,l0); split2(v.y,h1,l1); split2(v.z,h2,l2); split2(v.w,h3,l3);
    uint2 ph, pl;
    ph.x = (unsigned)h0 | ((unsigned)h1 << 16); ph.y = (unsigned)h2 | ((unsigned)h3 << 16);
    pl.x = (unsigned)l0 | ((unsigned)l1 << 16); pl.y = (unsigned)l2 | ((unsigned)l3 << 16);
    reinterpret_cast<uint2*>(dh)[e4] = ph;
    reinterpret_cast<uint2*>(dl)[e4] = pl;
  }
}

// ---------------- 128x128 split-bf16 NT GEMM (A[M][K], B[N][K]) ----------------
// 1D grid: blocks [0,nCompute) compute; the rest zero-fill fillp (overlaps compute).
// EPI=1: QKV epilogue; EPI=2: out-proj epilogue with scatter.
template<int EPI>
__global__ __launch_bounds__(256, 2) void gemm128(
    const unsigned short* __restrict__ Ah, const unsigned short* __restrict__ Al,
    const unsigned short* __restrict__ Bh, const unsigned short* __restrict__ Bl,
    const float* __restrict__ biasq, const float* __restrict__ biask, const float* __restrict__ biasv,
    unsigned short* __restrict__ qh, unsigned short* __restrict__ ql,
    unsigned short* __restrict__ kh, unsigned short* __restrict__ kl,
    unsigned short* __restrict__ vh,
    const float* __restrict__ biaso, const int* __restrict__ anc,
    float* __restrict__ outp,
    f32x4* __restrict__ fillp, int n4, int nCompute, int gcols)
{
  __shared__ unsigned short sAh[128 * 32], sAl[128 * 32], sBh[128 * 32], sBl[128 * 32];
  const int bidx = blockIdx.x;
  if (bidx >= nCompute) {
    const f32x4 z = {0.f, 0.f, 0.f, 0.f};
    int i = (bidx - nCompute) * 256 + threadIdx.x;
    for (; i < n4; i += FILLB * 256) __builtin_nontemporal_store(z, fillp + i);
    return;
  }
  const int tid = threadIdx.x, lane = tid & 63, w = tid >> 6;
  const int wr = w >> 1, wc = w & 1;
  // bijective XCD swizzle (nCompute % 8 == 0)
  const unsigned int wg = ((unsigned)bidx & 7) * ((unsigned)nCompute >> 3) + ((unsigned)bidx >> 3);
  const int m0 = (int)(wg / gcols) * 128, n0 = (int)(wg % gcols) * 128;
  const int rsel = lane & 15, kg = lane >> 4;
  f32x4 acc[4][4] = {};

  for (int k0 = 0; k0 < DM; k0 += 32) {
    __syncthreads();
    #pragma unroll
    for (int c = 0; c < 2; ++c) {
      const int gg = w * 128 + c * 64;           // wave-uniform granule base
      const int g = gg + lane;
      const int row = g >> 2, slot = g & 3;
      const int kk = k0 + ((slot ^ ((row >> 1) & 3)) << 3);
      const size_t aoff = (size_t)(m0 + row) * DM + kk;
      const size_t boff = (size_t)(n0 + row) * DM + kk;
      gld_lds16(Ah + aoff, sAh + gg * 8);
      gld_lds16(Al + aoff, sAl + gg * 8);
      gld_lds16(Bh + boff, sBh + gg * 8);
      gld_lds16(Bl + boff, sBl + gg * 8);
    }
    __syncthreads();
    s16x8 afh[4], afl[4], bfh[4], bfl[4];
    #pragma unroll
    for (int i = 0; i < 4; ++i) {
      const int row = wr * 64 + i * 16 + rsel;
      const int aoff = row * 32 + ((kg ^ ((row >> 1) & 3)) << 3);
      afh[i] = *reinterpret_cast<const s16x8*>(sAh + aoff);
      afl[i] = *reinterpret_cast<const s16x8*>(sAl + aoff);
      const int col = wc * 64 + i * 16 + rsel;
      const int boff2 = col * 32 + ((kg ^ ((col >> 1) & 3)) << 3);
      bfh[i] = *reinterpret_cast<const s16x8*>(sBh + boff2);
      bfl[i] = *reinterpret_cast<const s16x8*>(sBl + boff2);
    }
    #pragma unroll
    for (int i = 0; i < 4; ++i)
      #pragma unroll
      for (int j = 0; j < 4; ++j) {
        acc[i][j] = __builtin_amdgcn_mfma_f32_16x16x32_bf16(afh[i], bfh[j], acc[i][j], 0, 0, 0);
        acc[i][j] = __builtin_amdgcn_mfma_f32_16x16x32_bf16(afh[i], bfl[j], acc[i][j], 0, 0, 0);
        acc[i][j] = __builtin_amdgcn_mfma_f32_16x16x32_bf16(afl[i], bfh[j], acc[i][j], 0, 0, 0);
      }
  }

  #pragma unroll
  for (int i = 0; i < 4; ++i)
    #pragma unroll
    for (int j = 0; j < 4; ++j)
      #pragma unroll
      for (int r = 0; r < 4; ++r) {
        const int row = m0 + wr * 64 + i * 16 + kg * 4 + r;   // C/D: row=(l>>4)*4+reg
        const int col = n0 + wc * 64 + j * 16 + rsel;          //      col=l&15
        const float v = acc[i][j][r];
        const int b = row >> 9, a = row & (NA - 1);
        if (EPI == 1) {
          const int sec = (col >= 2 * DM) ? 2 : (col >= DM ? 1 : 0);
          const int f = col - sec * DM;
          const int hh = f / HDIM, d = f - hh * HDIM;
          const float* bp = (sec == 0) ? biasq : (sec == 1) ? biask : biasv;
          const float val = v + bp[f];
          unsigned short hi, lo; split2(val, hi, lo);
          const int bhh = b * NHEAD + hh;
          if (sec == 0)      { const size_t o = ((size_t)bhh * NA + a) * HDIM + d; qh[o] = hi; ql[o] = lo; }
          else if (sec == 1) { const size_t o = ((size_t)bhh * NA + a) * HDIM + d; kh[o] = hi; kl[o] = lo; }
          else               { const size_t o = ((size_t)bhh * HDIM + d) * NA + a; vh[o] = hi; }  // V^T, hi only
        } else {
          const int sidx = anc[b * NA + a];
          outp[((size_t)b * SEQ + sidx) * DM + col] = v + biaso[col];
        }
      }
}

// ---------------- fused attention: 32-row Q tiles, 64 KB LDS, 2 blocks/CU ----------
// QK^T 3-term (error-critical); softmax stores P as single RNE bf16 in the score
// slot's high 16 bits (in-place, same lane); PV single-term (P,V plain bf16).
__global__ __launch_bounds__(512, 4) void attn_fused(
    const unsigned short* __restrict__ qh, const unsigned short* __restrict__ ql,
    const unsigned short* __restrict__ kh, const unsigned short* __restrict__ kl,
    const unsigned short* __restrict__ vh,
    unsigned short* __restrict__ oh, unsigned short* __restrict__ ol)
{
  __shared__ unsigned int S[QBLK * 512];   // fp32 scores -> P bf16 (high16). 64 KiB
  __shared__ float rsum_lds[QBLK];
  const int blk = blockIdx.x;
  const int qt = blk & 15, bh = blk >> 4;
  const int b = bh >> 3, h = bh & 7;
  const int tid = threadIdx.x, lane = tid & 63, w = tid >> 6;
  const int rt = w & 1, ctq = w >> 1;    // QK^T: rows rt*16.., ct in [ctq*8, ctq*8+8)
  const int rsel = lane & 15, kg = lane >> 4;
  const int q0 = qt * QBLK;

  // Q fragments for this wave's 16 rows
  s16x8 qfh[3], qfl[3];
  {
    const size_t qrow = (size_t)bh * NA + q0 + rt * 16 + rsel;
    const unsigned short* qp  = qh + qrow * HDIM + kg * 8;
    const unsigned short* qp2 = ql + qrow * HDIM + kg * 8;
    #pragma unroll
    for (int kc = 0; kc < 3; ++kc) {
      qfh[kc] = *reinterpret_cast<const s16x8*>(qp  + kc * 32);
      qfl[kc] = *reinterpret_cast<const s16x8*>(qp2 + kc * 32);
    }
  }
  const float scale = 0.10206207261596575f;  // 1/sqrt(96)
  const unsigned short* kb_h = kh + (size_t)bh * NA * HDIM;
  const unsigned short* kb_l = kl + (size_t)bh * NA * HDIM;

  for (int ct2 = 0; ct2 < 8; ++ct2) {
    const int ct = ctq * 8 + ct2;
    f32x4 acc = {0.f, 0.f, 0.f, 0.f};
    const unsigned short* kp  = kb_h + (size_t)(ct * 16 + rsel) * HDIM + kg * 8;
    const unsigned short* kp2 = kb_l + (size_t)(ct * 16 + rsel) * HDIM + kg * 8;
    #pragma unroll
    for (int kc = 0; kc < 3; ++kc) {
      s16x8 kfh = *reinterpret_cast<const s16x8*>(kp  + kc * 32);
      s16x8 kfl = *reinterpret_cast<const s16x8*>(kp2 + kc * 32);
      __builtin_amdgcn_s_setprio(1);
      acc = __builtin_amdgcn_mfma_f32_16x16x32_bf16(qfh[kc], kfh, acc, 0, 0, 0);
      acc = __builtin_amdgcn_mfma_f32_16x16x32_bf16(qfh[kc], kfl, acc, 0, 0, 0);
      acc = __builtin_amdgcn_mfma_f32_16x16x32_bf16(qfl[kc], kfh, acc, 0, 0, 0);
      __builtin_amdgcn_s_setprio(0);
    }
    #pragma unroll
    for (int r = 0; r < 4; ++r) {
      int row = rt * 16 + kg * 4 + r;
      int col = ct * 16 + rsel;
      S[row * 512 + (col ^ ((row & 7) << 2))] = __float_as_uint(acc[r] * scale);
    }
  }
  __syncthreads();

  // softmax: wave w owns rows w*4..w*4+3; 16 lanes/row; interleaved cols (bank-floor)
  {
    const int row = w * 4 + (lane >> 4);
    const int sub = lane & 15;
    const int srow = (row & 7) << 2;
    unsigned int* rowp = &S[row * 512];
    float mx = -3.0e38f;
    #pragma unroll 8
    for (int i = 0; i < 8; ++i) {
      int c = sub * 4 + i * 64;
      uint4 u = *reinterpret_cast<const uint4*>(rowp + (c ^ srow));
      mx = fmaxf(mx, fmaxf(fmaxf(__uint_as_float(u.x), __uint_as_float(u.y)),
                           fmaxf(__uint_as_float(u.z), __uint_as_float(u.w))));
    }
    mx = fmaxf(mx, __shfl_xor(mx, 1));
    mx = fmaxf(mx, __shfl_xor(mx, 2));
    mx = fmaxf(mx, __shfl_xor(mx, 4));
    mx = fmaxf(mx, __shfl_xor(mx, 8));
    float sum = 0.f;
    #pragma unroll 8
    for (int i = 0; i < 8; ++i) {
      int c = sub * 4 + i * 64;
      uint4 u = *reinterpret_cast<const uint4*>(rowp + (c ^ srow));
      float p0 = __expf(__uint_as_float(u.x) - mx);
      float p1 = __expf(__uint_as_float(u.y) - mx);
      float p2 = __expf(__uint_as_float(u.z) - mx);
      float p3 = __expf(__uint_as_float(u.w) - mx);
      sum += p0 + p1 + p2 + p3;
      uint4 pk;
      pk.x = ((unsigned)f2bf(p0)) << 16;
      pk.y = ((unsigned)f2bf(p1)) << 16;
      pk.z = ((unsigned)f2bf(p2)) << 16;
      pk.w = ((unsigned)f2bf(p3)) << 16;
      *reinterpret_cast<uint4*>(rowp + (c ^ srow)) = pk;   // in-place, same lane
    }
    sum += __shfl_xor(sum, 1);
    sum += __shfl_xor(sum, 2);
    sum += __shfl_xor(sum, 4);
    sum += __shfl_xor(sum, 8);
    if (sub == 0) rsum_lds[row] = 1.f / sum;
  }
  __syncthreads();

  // O = P V : 12 tasks (rt2 x nt), round-robined over 8 waves; single-term
  const unsigned short* vb_h = vh + (size_t)bh * HDIM * NA;
  for (int task = w; task < 12; task += 8) {
    const int nt = task % 6, rt2 = task / 6;
    f32x4 acc = {0.f, 0.f, 0.f, 0.f};
    const int row = rt2 * 16 + rsel;
    const int srow = (row & 7) << 2;
    const unsigned int* rowp = &S[row * 512];
    for (int kc = 0; kc < 16; ++kc) {
      int c = kc * 32 + kg * 8;
      uint4 ua = *reinterpret_cast<const uint4*>(rowp + ((c) ^ srow));
      uint4 ub = *reinterpret_cast<const uint4*>(rowp + ((c + 4) ^ srow));
      s16x8 ph;
      ph[0] = (short)(ua.x >> 16); ph[1] = (short)(ua.y >> 16);
      ph[2] = (short)(ua.z >> 16); ph[3] = (short)(ua.w >> 16);
      ph[4] = (short)(ub.x >> 16); ph[5] = (short)(ub.y >> 16);
      ph[6] = (short)(ub.z >> 16); ph[7] = (short)(ub.w >> 16);
      const unsigned short* vp = vb_h + (size_t)(nt * 16 + rsel) * NA + c;
      s16x8 vfh = *reinterpret_cast<const s16x8*>(vp);
      __builtin_amdgcn_s_setprio(1);
      acc = __builtin_amdgcn_mfma_f32_16x16x32_bf16(ph, vfh, acc, 0, 0, 0);
      __builtin_amdgcn_s_setprio(0);
    }
    #pragma unroll
    for (int r = 0; r < 4; ++r) {
      const float rinv = rsum_lds[rt2 * 16 + kg * 4 + r];
      const int rowg = b * NA + q0 + rt2 * 16 + kg * 4 + r;
      float val = acc[r] * rinv;
      unsigned short hi, lo; split2(val, hi, lo);
      size_t o = (size_t)rowg * DM + h * HDIM + nt * 16 + rsel;
      oh[o] = hi; ol[o] = lo;
    }
  }
}

extern "C" void kernel_launch(void* const* d_in, const int* in_sizes, int n_in,
                              void* d_out, int out_size, void* d_ws, size_t ws_size,
                              hipStream_t stream)
{
  const float* hs   = (const float*)d_in[0];
  const int*   anc  = (const int*)d_in[1];
  const float* ln_g = (const float*)d_in[2];
  const float* ln_b = (const float*)d_in[3];
  const float* wq = (const float*)d_in[4];
  const float* bq = (const float*)d_in[5];
  const float* wk = (const float*)d_in[6];
  const float* bk = (const float*)d_in[7];
  const float* wv = (const float*)d_in[8];
  const float* bv = (const float*)d_in[9];
  const float* wo = (const float*)d_in[10];
  const float* bo = (const float*)d_in[11];
  float* outp = (float*)d_out;

  char* ws = (char*)d_ws;
  size_t off = 0;
  auto take = [&](size_t bytes) { char* p = ws + off; off += (bytes + 255) & ~(size_t)255; return p; };
  unsigned short* xh  = (unsigned short*)take((size_t)MROW * DM * 2);
  unsigned short* xl  = (unsigned short*)take((size_t)MROW * DM * 2);
  unsigned short* w1h = (unsigned short*)take((size_t)NQKV * DM * 2);
  unsigned short* w1l = (unsigned short*)take((size_t)NQKV * DM * 2);
  unsigned short* woh = (unsigned short*)take((size_t)DM * DM * 2);
  unsigned short* wol = (unsigned short*)take((size_t)DM * DM * 2);
  const size_t qkvsz = (size_t)NB * NHEAD * NA * HDIM * 2;
  unsigned short* qhb = (unsigned short*)take(qkvsz);
  unsigned short* qlb = (unsigned short*)take(qkvsz);
  unsigned short* khb = (unsigned short*)take(qkvsz);
  unsigned short* klb = (unsigned short*)take(qkvsz);
  unsigned short* vhb = (unsigned short*)take(qkvsz);
  unsigned short* ohb = (unsigned short*)take((size_t)MROW * DM * 2);
  unsigned short* olb = (unsigned short*)take((size_t)MROW * DM * 2);

  prologue<<<MROW + 2304, 256, 0, stream>>>(
      hs, anc, ln_g, ln_b, wq, wk, wv, wo,
      xh, xl, w1h, w1l, woh, wol);
  gemm128<1><<<(MROW / 128) * (NQKV / 128) + FILLB, 256, 0, stream>>>(
      xh, xl, w1h, w1l, bq, bk, bv, qhb, qlb, khb, klb, vhb,
      nullptr, nullptr, nullptr,
      (f32x4*)outp, out_size / 4, (MROW / 128) * (NQKV / 128), NQKV / 128);
  attn_fused<<<NB * NHEAD * (NA / QBLK), 512, 0, stream>>>(
      qhb, qlb, khb, klb, vhb, ohb, olb);
  gemm128<2><<<(MROW / 128) * (DM / 128), 256, 0, stream>>>(
      ohb, olb, woh, wol, nullptr, nullptr, nullptr,
      nullptr, nullptr, nullptr, nullptr, nullptr,
      bo, anc, outp,
      nullptr, 0, (MROW / 128) * (DM / 128), DM / 128);
}

// Round 6
// 154.913 us; speedup vs baseline: 1.7800x; 1.1570x over previous
//
#include <hip/hip_runtime.h>

#define DM 768
#define NHEAD 8
#define HDIM 96
#define NB 8
#define SEQ 8192
#define NA 512
#define MROW (NB*NA)      // 4096 anchor rows total
#define NQKV (3*DM)       // 2304
#define QBLK 32
#define FILLB 512         // fill blocks appended to gemm1's grid

typedef __attribute__((ext_vector_type(4))) float f32x4;
typedef __attribute__((ext_vector_type(8))) short s16x8;

static __device__ __forceinline__ unsigned short f2bf(float x) {
  unsigned int u = __float_as_uint(x);
  u += 0x7fffu + ((u >> 16) & 1u);          // RNE
  return (unsigned short)(u >> 16);
}
static __device__ __forceinline__ float bf2f(unsigned short h) {
  return __uint_as_float(((unsigned int)h) << 16);
}
static __device__ __forceinline__ void split2(float x, unsigned short& hi, unsigned short& lo) {
  hi = f2bf(x);
  lo = f2bf(x - bf2f(hi));                  // exact residual in fp32
}

static __device__ __forceinline__ void gld_lds16(const void* g, void* l) {
  __builtin_amdgcn_global_load_lds(
      (const __attribute__((address_space(1))) unsigned int*)g,
      (__attribute__((address_space(3))) unsigned int*)l, 16, 0, 0);
}

// ---------------- prologue: weight-split + gather+LN ----------------
__global__ __launch_bounds__(256) void prologue(
    const float* __restrict__ hs, const int* __restrict__ anc,
    const float* __restrict__ gam, const float* __restrict__ bet,
    const float* __restrict__ wq, const float* __restrict__ wk,
    const float* __restrict__ wv, const float* __restrict__ wo,
    unsigned short* __restrict__ xh,
    unsigned short* __restrict__ w1h, unsigned short* __restrict__ w1l,
    unsigned short* __restrict__ woh, unsigned short* __restrict__ wol)
{
  __shared__ float red[8];
  const int bid = blockIdx.x;
  const int t = threadIdx.x;
  if (bid < MROW) {
    // ---- gather + LayerNorm -> single bf16 (2-term GEMM drops the x_lo path) ----
    int r = bid;
    int b = r >> 9, a = r & (NA - 1);
    int idx = anc[b * NA + a];
    const float* src = hs + ((size_t)b * SEQ + idx) * DM;
    float e0 = src[t], e1 = src[t + 256], e2 = src[t + 512];
    float s = e0 + e1 + e2;
    float ss = e0*e0 + e1*e1 + e2*e2;
    #pragma unroll
    for (int o = 1; o < 64; o <<= 1) { s += __shfl_xor(s, o); ss += __shfl_xor(ss, o); }
    int w = t >> 6, lane = t & 63;
    if (lane == 0) { red[w] = s; red[4 + w] = ss; }
    __syncthreads();
    s  = red[0] + red[1] + red[2] + red[3];
    ss = red[4] + red[5] + red[6] + red[7];
    float mu = s * (1.f / DM);
    float var = ss * (1.f / DM) - mu * mu;   // biased, matches jnp.var
    float rstd = rsqrtf(var + 1e-5f);
    size_t base = (size_t)r * DM;
    #pragma unroll
    for (int p = 0; p < 3; ++p) {
      int c = t + p * 256;
      float e = (p == 0) ? e0 : (p == 1) ? e1 : e2;
      float y = (e - mu) * rstd * gam[c] + bet[c];
      xh[base + c] = f2bf(y);
    }
  } else {
    // ---- weight hi/lo split, float4 ----
    const int i = (bid - MROW) * 256 + t;    // float4 index
    const int T1_4 = (NQKV * DM) / 4;        // 442368
    const int TW_4 = (DM * DM) / 4;          // 147456
    float4 v;
    unsigned short* dh; unsigned short* dl; int e4;
    if (i < T1_4) {
      v = (i < TW_4) ? reinterpret_cast<const float4*>(wq)[i]
        : (i < 2*TW_4) ? reinterpret_cast<const float4*>(wk)[i - TW_4]
                       : reinterpret_cast<const float4*>(wv)[i - 2*TW_4];
      dh = w1h; dl = w1l; e4 = i;
    } else {
      int j = i - T1_4;
      v = reinterpret_cast<const float4*>(wo)[j];
      dh = woh; dl = wol; e4 = j;
    }
    unsigned short h0,l0,h1,l1,h2,l2,h3,l3;
    split2(v.x,h0,l0); split2(v.y,h1,l1); split2(v.z,h2,l2); split2(v.w,h3,l3);
    uint2 ph, pl;
    ph.x = (unsigned)h0 | ((unsigned)h1 << 16); ph.y = (unsigned)h2 | ((unsigned)h3 << 16);
    pl.x = (unsigned)l0 | ((unsigned)l1 << 16); pl.y = (unsigned)l2 | ((unsigned)l3 << 16);
    reinterpret_cast<uint2*>(dh)[e4] = ph;
    reinterpret_cast<uint2*>(dl)[e4] = pl;
  }
}

// ---------------- 128x128 2-term GEMM: A bf16, B split hi/lo, BK=64 ----------------
// D = A*(Bh+Bl): 2 MFMA per fragment pair. 12 K-iters (barriers halved vs BK=32).
// 1D grid: blocks [0,nCompute) compute; the rest zero-fill fillp (overlaps compute).
// EPI=1: QKV epilogue; EPI=2: out-proj epilogue with scatter.
template<int EPI>
__global__ __launch_bounds__(256, 3) void gemm128(
    const unsigned short* __restrict__ Ah,
    const unsigned short* __restrict__ Bh, const unsigned short* __restrict__ Bl,
    const float* __restrict__ biasq, const float* __restrict__ biask, const float* __restrict__ biasv,
    unsigned short* __restrict__ qh, unsigned short* __restrict__ ql,
    unsigned short* __restrict__ kh, unsigned short* __restrict__ kl,
    unsigned short* __restrict__ vh,
    const float* __restrict__ biaso, const int* __restrict__ anc,
    float* __restrict__ outp,
    f32x4* __restrict__ fillp, int n4, int nCompute, int gcols)
{
  __shared__ unsigned short sA[128 * 64], sBh[128 * 64], sBl[128 * 64];  // 48 KiB
  const int bidx = blockIdx.x;
  if (bidx >= nCompute) {
    const f32x4 z = {0.f, 0.f, 0.f, 0.f};
    int i = (bidx - nCompute) * 256 + threadIdx.x;
    for (; i < n4; i += FILLB * 256) __builtin_nontemporal_store(z, fillp + i);
    return;
  }
  const int tid = threadIdx.x, lane = tid & 63, w = tid >> 6;
  const int wr = w >> 1, wc = w & 1;
  // bijective XCD swizzle (nCompute % 8 == 0)
  const unsigned int wg = ((unsigned)bidx & 7) * ((unsigned)nCompute >> 3) + ((unsigned)bidx >> 3);
  const int m0 = (int)(wg / gcols) * 128, n0 = (int)(wg % gcols) * 128;
  const int rsel = lane & 15, kg = lane >> 4;
  f32x4 acc[4][4] = {};

  for (int k0 = 0; k0 < DM; k0 += 64) {
    __syncthreads();
    // stage 1024 granules/array; granule g: row=g>>3, LDS slot=g&7 holds global
    // k-chunk (slot ^ (row&7))  [XOR bank swizzle, conflict-free per 16-lane phase]
    #pragma unroll
    for (int c = 0; c < 4; ++c) {
      const int gg = w * 256 + c * 64;           // wave-uniform granule base
      const int g = gg + lane;
      const int row = g >> 3, slot = g & 7;
      const int kk = k0 + ((slot ^ (row & 7)) << 3);
      gld_lds16(Ah + (size_t)(m0 + row) * DM + kk, sA  + gg * 8);
      gld_lds16(Bh + (size_t)(n0 + row) * DM + kk, sBh + gg * 8);
      gld_lds16(Bl + (size_t)(n0 + row) * DM + kk, sBl + gg * 8);
    }
    __syncthreads();
    #pragma unroll
    for (int s = 0; s < 2; ++s) {               // two K=32 sub-steps within BK=64
      s16x8 af[4], bfh[4], bfl[4];
      #pragma unroll
      for (int i = 0; i < 4; ++i) {
        const int row = wr * 64 + i * 16 + rsel;
        const int as = (((s << 2) | kg) ^ (row & 7));
        af[i] = *reinterpret_cast<const s16x8*>(sA + row * 64 + as * 8);
        const int col = wc * 64 + i * 16 + rsel;
        const int bs = (((s << 2) | kg) ^ (col & 7));
        bfh[i] = *reinterpret_cast<const s16x8*>(sBh + col * 64 + bs * 8);
        bfl[i] = *reinterpret_cast<const s16x8*>(sBl + col * 64 + bs * 8);
      }
      #pragma unroll
      for (int i = 0; i < 4; ++i)
        #pragma unroll
        for (int j = 0; j < 4; ++j) {
          acc[i][j] = __builtin_amdgcn_mfma_f32_16x16x32_bf16(af[i], bfh[j], acc[i][j], 0, 0, 0);
          acc[i][j] = __builtin_amdgcn_mfma_f32_16x16x32_bf16(af[i], bfl[j], acc[i][j], 0, 0, 0);
        }
    }
  }

  #pragma unroll
  for (int i = 0; i < 4; ++i)
    #pragma unroll
    for (int j = 0; j < 4; ++j)
      #pragma unroll
      for (int r = 0; r < 4; ++r) {
        const int row = m0 + wr * 64 + i * 16 + kg * 4 + r;   // C/D: row=(l>>4)*4+reg
        const int col = n0 + wc * 64 + j * 16 + rsel;          //      col=l&15
        const float v = acc[i][j][r];
        const int b = row >> 9, a = row & (NA - 1);
        if (EPI == 1) {
          const int sec = (col >= 2 * DM) ? 2 : (col >= DM ? 1 : 0);
          const int f = col - sec * DM;
          const int hh = f / HDIM, d = f - hh * HDIM;
          const float* bp = (sec == 0) ? biasq : (sec == 1) ? biask : biasv;
          const float val = v + bp[f];
          unsigned short hi, lo; split2(val, hi, lo);
          const int bhh = b * NHEAD + hh;
          if (sec == 0)      { const size_t o = ((size_t)bhh * NA + a) * HDIM + d; qh[o] = hi; ql[o] = lo; }
          else if (sec == 1) { const size_t o = ((size_t)bhh * NA + a) * HDIM + d; kh[o] = hi; kl[o] = lo; }
          else               { const size_t o = ((size_t)bhh * HDIM + d) * NA + a; vh[o] = hi; }  // V^T, hi only
        } else {
          const int sidx = anc[b * NA + a];
          outp[((size_t)b * SEQ + sidx) * DM + col] = v + biaso[col];
        }
      }
}

// ---------------- fused attention: 32-row Q tiles, 64 KB LDS, 2 blocks/CU ----------
// QK^T 3-term (error-critical); softmax stores P as single RNE bf16 in the score
// slot's high 16 bits; PV single-term; O written as single bf16.
__global__ __launch_bounds__(512, 4) void attn_fused(
    const unsigned short* __restrict__ qh, const unsigned short* __restrict__ ql,
    const unsigned short* __restrict__ kh, const unsigned short* __restrict__ kl,
    const unsigned short* __restrict__ vh,
    unsigned short* __restrict__ oh)
{
  __shared__ unsigned int S[QBLK * 512];   // fp32 scores -> P bf16 (high16). 64 KiB
  __shared__ float rsum_lds[QBLK];
  const int blk = blockIdx.x;
  const int qt = blk & 15, bh = blk >> 4;
  const int b = bh >> 3, h = bh & 7;
  const int tid = threadIdx.x, lane = tid & 63, w = tid >> 6;
  const int rt = w & 1, ctq = w >> 1;    // QK^T: rows rt*16.., ct in [ctq*8, ctq*8+8)
  const int rsel = lane & 15, kg = lane >> 4;
  const int q0 = qt * QBLK;

  // Q fragments for this wave's 16 rows
  s16x8 qfh[3], qfl[3];
  {
    const size_t qrow = (size_t)bh * NA + q0 + rt * 16 + rsel;
    const unsigned short* qp  = qh + qrow * HDIM + kg * 8;
    const unsigned short* qp2 = ql + qrow * HDIM + kg * 8;
    #pragma unroll
    for (int kc = 0; kc < 3; ++kc) {
      qfh[kc] = *reinterpret_cast<const s16x8*>(qp  + kc * 32);
      qfl[kc] = *reinterpret_cast<const s16x8*>(qp2 + kc * 32);
    }
  }
  const float scale = 0.10206207261596575f;  // 1/sqrt(96)
  const unsigned short* kb_h = kh + (size_t)bh * NA * HDIM;
  const unsigned short* kb_l = kl + (size_t)bh * NA * HDIM;

  for (int ct2 = 0; ct2 < 8; ++ct2) {
    const int ct = ctq * 8 + ct2;
    f32x4 acc = {0.f, 0.f, 0.f, 0.f};
    const unsigned short* kp  = kb_h + (size_t)(ct * 16 + rsel) * HDIM + kg * 8;
    const unsigned short* kp2 = kb_l + (size_t)(ct * 16 + rsel) * HDIM + kg * 8;
    #pragma unroll
    for (int kc = 0; kc < 3; ++kc) {
      s16x8 kfh = *reinterpret_cast<const s16x8*>(kp  + kc * 32);
      s16x8 kfl = *reinterpret_cast<const s16x8*>(kp2 + kc * 32);
      __builtin_amdgcn_s_setprio(1);
      acc = __builtin_amdgcn_mfma_f32_16x16x32_bf16(qfh[kc], kfh, acc, 0, 0, 0);
      acc = __builtin_amdgcn_mfma_f32_16x16x32_bf16(qfh[kc], kfl, acc, 0, 0, 0);
      acc = __builtin_amdgcn_mfma_f32_16x16x32_bf16(qfl[kc], kfh, acc, 0, 0, 0);
      __builtin_amdgcn_s_setprio(0);
    }
    #pragma unroll
    for (int r = 0; r < 4; ++r) {
      int row = rt * 16 + kg * 4 + r;
      int col = ct * 16 + rsel;
      S[row * 512 + (col ^ ((row & 7) << 2))] = __float_as_uint(acc[r] * scale);
    }
  }
  __syncthreads();

  // softmax: wave w owns rows w*4..w*4+3; 16 lanes/row; interleaved cols (bank-floor)
  {
    const int row = w * 4 + (lane >> 4);
    const int sub = lane & 15;
    const int srow = (row & 7) << 2;
    unsigned int* rowp = &S[row * 512];
    float mx = -3.0e38f;
    #pragma unroll 8
    for (int i = 0; i < 8; ++i) {
      int c = sub * 4 + i * 64;
      uint4 u = *reinterpret_cast<const uint4*>(rowp + (c ^ srow));
      mx = fmaxf(mx, fmaxf(fmaxf(__uint_as_float(u.x), __uint_as_float(u.y)),
                           fmaxf(__uint_as_float(u.z), __uint_as_float(u.w))));
    }
    mx = fmaxf(mx, __shfl_xor(mx, 1));
    mx = fmaxf(mx, __shfl_xor(mx, 2));
    mx = fmaxf(mx, __shfl_xor(mx, 4));
    mx = fmaxf(mx, __shfl_xor(mx, 8));
    float sum = 0.f;
    #pragma unroll 8
    for (int i = 0; i < 8; ++i) {
      int c = sub * 4 + i * 64;
      uint4 u = *reinterpret_cast<const uint4*>(rowp + (c ^ srow));
      float p0 = __expf(__uint_as_float(u.x) - mx);
      float p1 = __expf(__uint_as_float(u.y) - mx);
      float p2 = __expf(__uint_as_float(u.z) - mx);
      float p3 = __expf(__uint_as_float(u.w) - mx);
      sum += p0 + p1 + p2 + p3;
      uint4 pk;
      pk.x = ((unsigned)f2bf(p0)) << 16;
      pk.y = ((unsigned)f2bf(p1)) << 16;
      pk.z = ((unsigned)f2bf(p2)) << 16;
      pk.w = ((unsigned)f2bf(p3)) << 16;
      *reinterpret_cast<uint4*>(rowp + (c ^ srow)) = pk;   // in-place, same lane
    }
    sum += __shfl_xor(sum, 1);
    sum += __shfl_xor(sum, 2);
    sum += __shfl_xor(sum, 4);
    sum += __shfl_xor(sum, 8);
    if (sub == 0) rsum_lds[row] = 1.f / sum;
  }
  __syncthreads();

  // O = P V : 12 tasks (rt2 x nt), round-robined over 8 waves; single-term
  const unsigned short* vb_h = vh + (size_t)bh * HDIM * NA;
  for (int task = w; task < 12; task += 8) {
    const int nt = task % 6, rt2 = task / 6;
    f32x4 acc = {0.f, 0.f, 0.f, 0.f};
    const int row = rt2 * 16 + rsel;
    const int srow = (row & 7) << 2;
    const unsigned int* rowp = &S[row * 512];
    for (int kc = 0; kc < 16; ++kc) {
      int c = kc * 32 + kg * 8;
      uint4 ua = *reinterpret_cast<const uint4*>(rowp + ((c) ^ srow));
      uint4 ub = *reinterpret_cast<const uint4*>(rowp + ((c + 4) ^ srow));
      s16x8 ph;
      ph[0] = (short)(ua.x >> 16); ph[1] = (short)(ua.y >> 16);
      ph[2] = (short)(ua.z >> 16); ph[3] = (short)(ua.w >> 16);
      ph[4] = (short)(ub.x >> 16); ph[5] = (short)(ub.y >> 16);
      ph[6] = (short)(ub.z >> 16); ph[7] = (short)(ub.w >> 16);
      const unsigned short* vp = vb_h + (size_t)(nt * 16 + rsel) * NA + c;
      s16x8 vfh = *reinterpret_cast<const s16x8*>(vp);
      __builtin_amdgcn_s_setprio(1);
      acc = __builtin_amdgcn_mfma_f32_16x16x32_bf16(ph, vfh, acc, 0, 0, 0);
      __builtin_amdgcn_s_setprio(0);
    }
    #pragma unroll
    for (int r = 0; r < 4; ++r) {
      const float rinv = rsum_lds[rt2 * 16 + kg * 4 + r];
      const int rowg = b * NA + q0 + rt2 * 16 + kg * 4 + r;
      size_t o = (size_t)rowg * DM + h * HDIM + nt * 16 + rsel;
      oh[o] = f2bf(acc[r] * rinv);
    }
  }
}

extern "C" void kernel_launch(void* const* d_in, const int* in_sizes, int n_in,
                              void* d_out, int out_size, void* d_ws, size_t ws_size,
                              hipStream_t stream)
{
  const float* hs   = (const float*)d_in[0];
  const int*   anc  = (const int*)d_in[1];
  const float* ln_g = (const float*)d_in[2];
  const float* ln_b = (const float*)d_in[3];
  const float* wq = (const float*)d_in[4];
  const float* bq = (const float*)d_in[5];
  const float* wk = (const float*)d_in[6];
  const float* bk = (const float*)d_in[7];
  const float* wv = (const float*)d_in[8];
  const float* bv = (const float*)d_in[9];
  const float* wo = (const float*)d_in[10];
  const float* bo = (const float*)d_in[11];
  float* outp = (float*)d_out;

  char* ws = (char*)d_ws;
  size_t off = 0;
  auto take = [&](size_t bytes) { char* p = ws + off; off += (bytes + 255) & ~(size_t)255; return p; };
  unsigned short* xh  = (unsigned short*)take((size_t)MROW * DM * 2);
  unsigned short* w1h = (unsigned short*)take((size_t)NQKV * DM * 2);
  unsigned short* w1l = (unsigned short*)take((size_t)NQKV * DM * 2);
  unsigned short* woh = (unsigned short*)take((size_t)DM * DM * 2);
  unsigned short* wol = (unsigned short*)take((size_t)DM * DM * 2);
  const size_t qkvsz = (size_t)NB * NHEAD * NA * HDIM * 2;
  unsigned short* qhb = (unsigned short*)take(qkvsz);
  unsigned short* qlb = (unsigned short*)take(qkvsz);
  unsigned short* khb = (unsigned short*)take(qkvsz);
  unsigned short* klb = (unsigned short*)take(qkvsz);
  unsigned short* vhb = (unsigned short*)take(qkvsz);
  unsigned short* ohb = (unsigned short*)take((size_t)MROW * DM * 2);

  prologue<<<MROW + 2304, 256, 0, stream>>>(
      hs, anc, ln_g, ln_b, wq, wk, wv, wo,
      xh, w1h, w1l, woh, wol);
  gemm128<1><<<(MROW / 128) * (NQKV / 128) + FILLB, 256, 0, stream>>>(
      xh, w1h, w1l, bq, bk, bv, qhb, qlb, khb, klb, vhb,
      nullptr, nullptr, nullptr,
      (f32x4*)outp, out_size / 4, (MROW / 128) * (NQKV / 128), NQKV / 128);
  attn_fused<<<NB * NHEAD * (NA / QBLK), 512, 0, stream>>>(
      qhb, qlb, khb, klb, vhb, ohb);
  gemm128<2><<<(MROW / 128) * (DM / 128), 256, 0, stream>>>(
      ohb, woh, wol, nullptr, nullptr, nullptr,
      nullptr, nullptr, nullptr, nullptr, nullptr,
      bo, anc, outp,
      nullptr, 0, (MROW / 128) * (DM / 128), DM / 128);
}

// Round 7
// 129.121 us; speedup vs baseline: 2.1356x; 1.1998x over previous
//
#include <hip/hip_runtime.h>

#define DM 768
#define NHEAD 8
#define HDIM 96
#define NB 8
#define SEQ 8192
#define NA 512
#define MROW (NB*NA)      // 4096 anchor rows total
#define NQKV (3*DM)       // 2304
#define QBLK 32
#define FILLB 512         // fill blocks appended to gemm1's grid

typedef __attribute__((ext_vector_type(4))) float f32x4;
typedef __attribute__((ext_vector_type(8))) short s16x8;

static __device__ __forceinline__ unsigned short f2bf(float x) {
  unsigned int u = __float_as_uint(x);
  u += 0x7fffu + ((u >> 16) & 1u);          // RNE
  return (unsigned short)(u >> 16);
}
static __device__ __forceinline__ float bf2f(unsigned short h) {
  return __uint_as_float(((unsigned int)h) << 16);
}
static __device__ __forceinline__ void split2(float x, unsigned short& hi, unsigned short& lo) {
  hi = f2bf(x);
  lo = f2bf(x - bf2f(hi));                  // exact residual in fp32
}

static __device__ __forceinline__ void gld_lds16(const void* g, void* l) {
  __builtin_amdgcn_global_load_lds(
      (const __attribute__((address_space(1))) unsigned int*)g,
      (__attribute__((address_space(3))) unsigned int*)l, 16, 0, 0);
}

// ---------------- prologue: weight f32->bf16 convert + gather+LN ----------------
__global__ __launch_bounds__(256) void prologue(
    const float* __restrict__ hs, const int* __restrict__ anc,
    const float* __restrict__ gam, const float* __restrict__ bet,
    const float* __restrict__ wq, const float* __restrict__ wk,
    const float* __restrict__ wv, const float* __restrict__ wo,
    unsigned short* __restrict__ xh,
    unsigned short* __restrict__ w1h, unsigned short* __restrict__ woh)
{
  __shared__ float red[8];
  const int bid = blockIdx.x;
  const int t = threadIdx.x;
  if (bid < MROW) {
    // ---- gather + LayerNorm -> single bf16 ----
    int r = bid;
    int b = r >> 9, a = r & (NA - 1);
    int idx = anc[b * NA + a];
    const float* src = hs + ((size_t)b * SEQ + idx) * DM;
    float e0 = src[t], e1 = src[t + 256], e2 = src[t + 512];
    float s = e0 + e1 + e2;
    float ss = e0*e0 + e1*e1 + e2*e2;
    #pragma unroll
    for (int o = 1; o < 64; o <<= 1) { s += __shfl_xor(s, o); ss += __shfl_xor(ss, o); }
    int w = t >> 6, lane = t & 63;
    if (lane == 0) { red[w] = s; red[4 + w] = ss; }
    __syncthreads();
    s  = red[0] + red[1] + red[2] + red[3];
    ss = red[4] + red[5] + red[6] + red[7];
    float mu = s * (1.f / DM);
    float var = ss * (1.f / DM) - mu * mu;   // biased, matches jnp.var
    float rstd = rsqrtf(var + 1e-5f);
    size_t base = (size_t)r * DM;
    #pragma unroll
    for (int p = 0; p < 3; ++p) {
      int c = t + p * 256;
      float e = (p == 0) ? e0 : (p == 1) ? e1 : e2;
      float y = (e - mu) * rstd * gam[c] + bet[c];
      xh[base + c] = f2bf(y);
    }
  } else {
    // ---- weight f32 -> bf16 (single), float4-vectorized ----
    const int i = (bid - MROW) * 256 + t;    // float4 index
    const int T1_4 = (NQKV * DM) / 4;        // 442368
    const int TW_4 = (DM * DM) / 4;          // 147456
    float4 v;
    unsigned short* dh; int e4;
    if (i < T1_4) {
      v = (i < TW_4) ? reinterpret_cast<const float4*>(wq)[i]
        : (i < 2*TW_4) ? reinterpret_cast<const float4*>(wk)[i - TW_4]
                       : reinterpret_cast<const float4*>(wv)[i - 2*TW_4];
      dh = w1h; e4 = i;
    } else {
      int j = i - T1_4;
      v = reinterpret_cast<const float4*>(wo)[j];
      dh = woh; e4 = j;
    }
    uint2 ph;
    ph.x = (unsigned)f2bf(v.x) | ((unsigned)f2bf(v.y) << 16);
    ph.y = (unsigned)f2bf(v.z) | ((unsigned)f2bf(v.w) << 16);
    reinterpret_cast<uint2*>(dh)[e4] = ph;
  }
}

// ---------------- 128x128 single-bf16 NT GEMM, BK=64, 32 KiB LDS ----------------
// 1 MFMA per fragment pair; fp32 accumulate. 1D grid: blocks >= nCompute zero-fill.
// EPI=1: QKV epilogue (q hi; k hi/lo for attn 2-term; V^T hi). EPI=2: scatter out.
template<int EPI>
__global__ __launch_bounds__(256, 4) void gemm128(
    const unsigned short* __restrict__ Ah,
    const unsigned short* __restrict__ Bh,
    const float* __restrict__ biasq, const float* __restrict__ biask, const float* __restrict__ biasv,
    unsigned short* __restrict__ qh,
    unsigned short* __restrict__ kh, unsigned short* __restrict__ kl,
    unsigned short* __restrict__ vh,
    const float* __restrict__ biaso, const int* __restrict__ anc,
    float* __restrict__ outp,
    f32x4* __restrict__ fillp, int n4, int nCompute, int gcols)
{
  __shared__ unsigned short sA[128 * 64], sB[128 * 64];  // 32 KiB
  const int bidx = blockIdx.x;
  if (bidx >= nCompute) {
    const f32x4 z = {0.f, 0.f, 0.f, 0.f};
    int i = (bidx - nCompute) * 256 + threadIdx.x;
    for (; i < n4; i += FILLB * 256) __builtin_nontemporal_store(z, fillp + i);
    return;
  }
  const int tid = threadIdx.x, lane = tid & 63, w = tid >> 6;
  const int wr = w >> 1, wc = w & 1;
  // bijective XCD swizzle (nCompute % 8 == 0)
  const unsigned int wg = ((unsigned)bidx & 7) * ((unsigned)nCompute >> 3) + ((unsigned)bidx >> 3);
  const int m0 = (int)(wg / gcols) * 128, n0 = (int)(wg % gcols) * 128;
  const int rsel = lane & 15, kg = lane >> 4;
  f32x4 acc[4][4] = {};

  for (int k0 = 0; k0 < DM; k0 += 64) {
    __syncthreads();
    // stage 1024 granules/array; granule g: row=g>>3, LDS slot=g&7 holds global
    // k-chunk (slot ^ (row&7))  [XOR bank swizzle]
    #pragma unroll
    for (int c = 0; c < 4; ++c) {
      const int gg = w * 256 + c * 64;           // wave-uniform granule base
      const int g = gg + lane;
      const int row = g >> 3, slot = g & 7;
      const int kk = k0 + ((slot ^ (row & 7)) << 3);
      gld_lds16(Ah + (size_t)(m0 + row) * DM + kk, sA + gg * 8);
      gld_lds16(Bh + (size_t)(n0 + row) * DM + kk, sB + gg * 8);
    }
    __syncthreads();
    #pragma unroll
    for (int s = 0; s < 2; ++s) {               // two K=32 sub-steps within BK=64
      s16x8 af[4], bf[4];
      #pragma unroll
      for (int i = 0; i < 4; ++i) {
        const int row = wr * 64 + i * 16 + rsel;
        const int as = (((s << 2) | kg) ^ (row & 7));
        af[i] = *reinterpret_cast<const s16x8*>(sA + row * 64 + as * 8);
        const int col = wc * 64 + i * 16 + rsel;
        const int bs = (((s << 2) | kg) ^ (col & 7));
        bf[i] = *reinterpret_cast<const s16x8*>(sB + col * 64 + bs * 8);
      }
      #pragma unroll
      for (int i = 0; i < 4; ++i)
        #pragma unroll
        for (int j = 0; j < 4; ++j)
          acc[i][j] = __builtin_amdgcn_mfma_f32_16x16x32_bf16(af[i], bf[j], acc[i][j], 0, 0, 0);
    }
  }

  #pragma unroll
  for (int i = 0; i < 4; ++i)
    #pragma unroll
    for (int j = 0; j < 4; ++j)
      #pragma unroll
      for (int r = 0; r < 4; ++r) {
        const int row = m0 + wr * 64 + i * 16 + kg * 4 + r;   // C/D: row=(l>>4)*4+reg
        const int col = n0 + wc * 64 + j * 16 + rsel;          //      col=l&15
        const float v = acc[i][j][r];
        const int b = row >> 9, a = row & (NA - 1);
        if (EPI == 1) {
          const int sec = (col >= 2 * DM) ? 2 : (col >= DM ? 1 : 0);
          const int f = col - sec * DM;
          const int hh = f / HDIM, d = f - hh * HDIM;
          const float* bp = (sec == 0) ? biasq : (sec == 1) ? biask : biasv;
          const float val = v + bp[f];
          const int bhh = b * NHEAD + hh;
          if (sec == 0) {
            const size_t o = ((size_t)bhh * NA + a) * HDIM + d; qh[o] = f2bf(val);
          } else if (sec == 1) {
            unsigned short hi, lo; split2(val, hi, lo);
            const size_t o = ((size_t)bhh * NA + a) * HDIM + d; kh[o] = hi; kl[o] = lo;
          } else {
            const size_t o = ((size_t)bhh * HDIM + d) * NA + a; vh[o] = f2bf(val);  // V^T
          }
        } else {
          const int sidx = anc[b * NA + a];
          outp[((size_t)b * SEQ + sidx) * DM + col] = v + biaso[col];
        }
      }
}

// ---------------- fused attention: 32-row Q tiles, 64 KB LDS, 2 blocks/CU ----------
// QK^T 2-term (q_hi x (k_hi + k_lo)); fp32 softmax; PV single-term; O single bf16.
__global__ __launch_bounds__(512, 4) void attn_fused(
    const unsigned short* __restrict__ qh,
    const unsigned short* __restrict__ kh, const unsigned short* __restrict__ kl,
    const unsigned short* __restrict__ vh,
    unsigned short* __restrict__ oh)
{
  __shared__ unsigned int S[QBLK * 512];   // fp32 scores -> P bf16 (high16). 64 KiB
  __shared__ float rsum_lds[QBLK];
  const int blk = blockIdx.x;
  const int qt = blk & 15, bh = blk >> 4;
  const int b = bh >> 3, h = bh & 7;
  const int tid = threadIdx.x, lane = tid & 63, w = tid >> 6;
  const int rt = w & 1, ctq = w >> 1;    // QK^T: rows rt*16.., ct in [ctq*8, ctq*8+8)
  const int rsel = lane & 15, kg = lane >> 4;
  const int q0 = qt * QBLK;

  // Q fragments for this wave's 16 rows (single bf16)
  s16x8 qf[3];
  {
    const size_t qrow = (size_t)bh * NA + q0 + rt * 16 + rsel;
    const unsigned short* qp = qh + qrow * HDIM + kg * 8;
    #pragma unroll
    for (int kc = 0; kc < 3; ++kc)
      qf[kc] = *reinterpret_cast<const s16x8*>(qp + kc * 32);
  }
  const float scale = 0.10206207261596575f;  // 1/sqrt(96)
  const unsigned short* kb_h = kh + (size_t)bh * NA * HDIM;
  const unsigned short* kb_l = kl + (size_t)bh * NA * HDIM;

  for (int ct2 = 0; ct2 < 8; ++ct2) {
    const int ct = ctq * 8 + ct2;
    f32x4 acc = {0.f, 0.f, 0.f, 0.f};
    const unsigned short* kp  = kb_h + (size_t)(ct * 16 + rsel) * HDIM + kg * 8;
    const unsigned short* kp2 = kb_l + (size_t)(ct * 16 + rsel) * HDIM + kg * 8;
    #pragma unroll
    for (int kc = 0; kc < 3; ++kc) {
      s16x8 kfh = *reinterpret_cast<const s16x8*>(kp  + kc * 32);
      s16x8 kfl = *reinterpret_cast<const s16x8*>(kp2 + kc * 32);
      __builtin_amdgcn_s_setprio(1);
      acc = __builtin_amdgcn_mfma_f32_16x16x32_bf16(qf[kc], kfh, acc, 0, 0, 0);
      acc = __builtin_amdgcn_mfma_f32_16x16x32_bf16(qf[kc], kfl, acc, 0, 0, 0);
      __builtin_amdgcn_s_setprio(0);
    }
    #pragma unroll
    for (int r = 0; r < 4; ++r) {
      int row = rt * 16 + kg * 4 + r;
      int col = ct * 16 + rsel;
      S[row * 512 + (col ^ ((row & 7) << 2))] = __float_as_uint(acc[r] * scale);
    }
  }
  __syncthreads();

  // softmax: wave w owns rows w*4..w*4+3; 16 lanes/row; interleaved cols (bank-floor)
  {
    const int row = w * 4 + (lane >> 4);
    const int sub = lane & 15;
    const int srow = (row & 7) << 2;
    unsigned int* rowp = &S[row * 512];
    float mx = -3.0e38f;
    #pragma unroll 8
    for (int i = 0; i < 8; ++i) {
      int c = sub * 4 + i * 64;
      uint4 u = *reinterpret_cast<const uint4*>(rowp + (c ^ srow));
      mx = fmaxf(mx, fmaxf(fmaxf(__uint_as_float(u.x), __uint_as_float(u.y)),
                           fmaxf(__uint_as_float(u.z), __uint_as_float(u.w))));
    }
    mx = fmaxf(mx, __shfl_xor(mx, 1));
    mx = fmaxf(mx, __shfl_xor(mx, 2));
    mx = fmaxf(mx, __shfl_xor(mx, 4));
    mx = fmaxf(mx, __shfl_xor(mx, 8));
    float sum = 0.f;
    #pragma unroll 8
    for (int i = 0; i < 8; ++i) {
      int c = sub * 4 + i * 64;
      uint4 u = *reinterpret_cast<const uint4*>(rowp + (c ^ srow));
      float p0 = __expf(__uint_as_float(u.x) - mx);
      float p1 = __expf(__uint_as_float(u.y) - mx);
      float p2 = __expf(__uint_as_float(u.z) - mx);
      float p3 = __expf(__uint_as_float(u.w) - mx);
      sum += p0 + p1 + p2 + p3;
      uint4 pk;
      pk.x = ((unsigned)f2bf(p0)) << 16;
      pk.y = ((unsigned)f2bf(p1)) << 16;
      pk.z = ((unsigned)f2bf(p2)) << 16;
      pk.w = ((unsigned)f2bf(p3)) << 16;
      *reinterpret_cast<uint4*>(rowp + (c ^ srow)) = pk;   // in-place, same lane
    }
    sum += __shfl_xor(sum, 1);
    sum += __shfl_xor(sum, 2);
    sum += __shfl_xor(sum, 4);
    sum += __shfl_xor(sum, 8);
    if (sub == 0) rsum_lds[row] = 1.f / sum;
  }
  __syncthreads();

  // O = P V : 12 tasks (rt2 x nt), round-robined over 8 waves; single-term
  const unsigned short* vb_h = vh + (size_t)bh * HDIM * NA;
  for (int task = w; task < 12; task += 8) {
    const int nt = task % 6, rt2 = task / 6;
    f32x4 acc = {0.f, 0.f, 0.f, 0.f};
    const int row = rt2 * 16 + rsel;
    const int srow = (row & 7) << 2;
    const unsigned int* rowp = &S[row * 512];
    for (int kc = 0; kc < 16; ++kc) {
      int c = kc * 32 + kg * 8;
      uint4 ua = *reinterpret_cast<const uint4*>(rowp + ((c) ^ srow));
      uint4 ub = *reinterpret_cast<const uint4*>(rowp + ((c + 4) ^ srow));
      s16x8 ph;
      ph[0] = (short)(ua.x >> 16); ph[1] = (short)(ua.y >> 16);
      ph[2] = (short)(ua.z >> 16); ph[3] = (short)(ua.w >> 16);
      ph[4] = (short)(ub.x >> 16); ph[5] = (short)(ub.y >> 16);
      ph[6] = (short)(ub.z >> 16); ph[7] = (short)(ub.w >> 16);
      const unsigned short* vp = vb_h + (size_t)(nt * 16 + rsel) * NA + c;
      s16x8 vfh = *reinterpret_cast<const s16x8*>(vp);
      __builtin_amdgcn_s_setprio(1);
      acc = __builtin_amdgcn_mfma_f32_16x16x32_bf16(ph, vfh, acc, 0, 0, 0);
      __builtin_amdgcn_s_setprio(0);
    }
    #pragma unroll
    for (int r = 0; r < 4; ++r) {
      const float rinv = rsum_lds[rt2 * 16 + kg * 4 + r];
      const int rowg = b * NA + q0 + rt2 * 16 + kg * 4 + r;
      size_t o = (size_t)rowg * DM + h * HDIM + nt * 16 + rsel;
      oh[o] = f2bf(acc[r] * rinv);
    }
  }
}

extern "C" void kernel_launch(void* const* d_in, const int* in_sizes, int n_in,
                              void* d_out, int out_size, void* d_ws, size_t ws_size,
                              hipStream_t stream)
{
  const float* hs   = (const float*)d_in[0];
  const int*   anc  = (const int*)d_in[1];
  const float* ln_g = (const float*)d_in[2];
  const float* ln_b = (const float*)d_in[3];
  const float* wq = (const float*)d_in[4];
  const float* bq = (const float*)d_in[5];
  const float* wk = (const float*)d_in[6];
  const float* bk = (const float*)d_in[7];
  const float* wv = (const float*)d_in[8];
  const float* bv = (const float*)d_in[9];
  const float* wo = (const float*)d_in[10];
  const float* bo = (const float*)d_in[11];
  float* outp = (float*)d_out;

  char* ws = (char*)d_ws;
  size_t off = 0;
  auto take = [&](size_t bytes) { char* p = ws + off; off += (bytes + 255) & ~(size_t)255; return p; };
  unsigned short* xh  = (unsigned short*)take((size_t)MROW * DM * 2);
  unsigned short* w1h = (unsigned short*)take((size_t)NQKV * DM * 2);
  unsigned short* woh = (unsigned short*)take((size_t)DM * DM * 2);
  const size_t qkvsz = (size_t)NB * NHEAD * NA * HDIM * 2;
  unsigned short* qhb = (unsigned short*)take(qkvsz);
  unsigned short* khb = (unsigned short*)take(qkvsz);
  unsigned short* klb = (unsigned short*)take(qkvsz);
  unsigned short* vhb = (unsigned short*)take(qkvsz);
  unsigned short* ohb = (unsigned short*)take((size_t)MROW * DM * 2);

  prologue<<<MROW + 2304, 256, 0, stream>>>(
      hs, anc, ln_g, ln_b, wq, wk, wv, wo, xh, w1h, woh);
  gemm128<1><<<(MROW / 128) * (NQKV / 128) + FILLB, 256, 0, stream>>>(
      xh, w1h, bq, bk, bv, qhb, khb, klb, vhb,
      nullptr, nullptr, nullptr,
      (f32x4*)outp, out_size / 4, (MROW / 128) * (NQKV / 128), NQKV / 128);
  attn_fused<<<NB * NHEAD * (NA / QBLK), 512, 0, stream>>>(
      qhb, khb, klb, vhb, ohb);
  gemm128<2><<<(MROW / 128) * (DM / 128), 256, 0, stream>>>(
      ohb, woh, nullptr, nullptr, nullptr,
      nullptr, nullptr, nullptr, nullptr,
      bo, anc, outp,
      nullptr, 0, (MROW / 128) * (DM / 128), DM / 128);
}

// Round 8
// 117.778 us; speedup vs baseline: 2.3413x; 1.0963x over previous
//
#include <hip/hip_runtime.h>

#define DM 768
#define NHEAD 8
#define HDIM 96
#define NB 8
#define SEQ 8192
#define NA 512
#define MROW (NB*NA)      // 4096 anchor rows total
#define NQKV (3*DM)       // 2304
#define QBLK 32
#define FILLB 512         // fill blocks appended to gemm1's grid

typedef __attribute__((ext_vector_type(4))) float f32x4;
typedef __attribute__((ext_vector_type(8))) short s16x8;

static __device__ __forceinline__ unsigned short f2bf(float x) {
  unsigned int u = __float_as_uint(x);
  u += 0x7fffu + ((u >> 16) & 1u);          // RNE
  return (unsigned short)(u >> 16);
}
static __device__ __forceinline__ float bf2f(unsigned short h) {
  return __uint_as_float(((unsigned int)h) << 16);
}

static __device__ __forceinline__ void gld_lds16(const void* g, void* l) {
  __builtin_amdgcn_global_load_lds(
      (const __attribute__((address_space(1))) unsigned int*)g,
      (__attribute__((address_space(3))) unsigned int*)l, 16, 0, 0);
}

// ---------------- prologue: weight f32->bf16 convert + gather+LN ----------------
__global__ __launch_bounds__(256) void prologue(
    const float* __restrict__ hs, const int* __restrict__ anc,
    const float* __restrict__ gam, const float* __restrict__ bet,
    const float* __restrict__ wq, const float* __restrict__ wk,
    const float* __restrict__ wv, const float* __restrict__ wo,
    unsigned short* __restrict__ xh,
    unsigned short* __restrict__ w1h, unsigned short* __restrict__ woh)
{
  __shared__ float red[8];
  const int bid = blockIdx.x;
  const int t = threadIdx.x;
  if (bid < MROW) {
    // ---- gather + LayerNorm -> single bf16 ----
    int r = bid;
    int b = r >> 9, a = r & (NA - 1);
    int idx = anc[b * NA + a];
    const float* src = hs + ((size_t)b * SEQ + idx) * DM;
    float e0 = src[t], e1 = src[t + 256], e2 = src[t + 512];
    float s = e0 + e1 + e2;
    float ss = e0*e0 + e1*e1 + e2*e2;
    #pragma unroll
    for (int o = 1; o < 64; o <<= 1) { s += __shfl_xor(s, o); ss += __shfl_xor(ss, o); }
    int w = t >> 6, lane = t & 63;
    if (lane == 0) { red[w] = s; red[4 + w] = ss; }
    __syncthreads();
    s  = red[0] + red[1] + red[2] + red[3];
    ss = red[4] + red[5] + red[6] + red[7];
    float mu = s * (1.f / DM);
    float var = ss * (1.f / DM) - mu * mu;   // biased, matches jnp.var
    float rstd = rsqrtf(var + 1e-5f);
    size_t base = (size_t)r * DM;
    #pragma unroll
    for (int p = 0; p < 3; ++p) {
      int c = t + p * 256;
      float e = (p == 0) ? e0 : (p == 1) ? e1 : e2;
      float y = (e - mu) * rstd * gam[c] + bet[c];
      xh[base + c] = f2bf(y);
    }
  } else {
    // ---- weight f32 -> bf16 (single), float4-vectorized ----
    const int i = (bid - MROW) * 256 + t;    // float4 index
    const int T1_4 = (NQKV * DM) / 4;        // 442368
    const int TW_4 = (DM * DM) / 4;          // 147456
    float4 v;
    unsigned short* dh; int e4;
    if (i < T1_4) {
      v = (i < TW_4) ? reinterpret_cast<const float4*>(wq)[i]
        : (i < 2*TW_4) ? reinterpret_cast<const float4*>(wk)[i - TW_4]
                       : reinterpret_cast<const float4*>(wv)[i - 2*TW_4];
      dh = w1h; e4 = i;
    } else {
      int j = i - T1_4;
      v = reinterpret_cast<const float4*>(wo)[j];
      dh = woh; e4 = j;
    }
    uint2 ph;
    ph.x = (unsigned)f2bf(v.x) | ((unsigned)f2bf(v.y) << 16);
    ph.y = (unsigned)f2bf(v.z) | ((unsigned)f2bf(v.w) << 16);
    reinterpret_cast<uint2*>(dh)[e4] = ph;
  }
}

// ---------------- 128x128 single-bf16 NT GEMM, BK=64, 32 KiB LDS ----------------
// 1 MFMA per fragment pair; fp32 accumulate. 1D grid: blocks >= nCompute zero-fill.
// EPI=1: QKV epilogue (q/k/V^T bf16). EPI=2: scatter out.
template<int EPI>
__global__ __launch_bounds__(256, 4) void gemm128(
    const unsigned short* __restrict__ Ah,
    const unsigned short* __restrict__ Bh,
    const float* __restrict__ biasq, const float* __restrict__ biask, const float* __restrict__ biasv,
    unsigned short* __restrict__ qh,
    unsigned short* __restrict__ kh,
    unsigned short* __restrict__ vh,
    const float* __restrict__ biaso, const int* __restrict__ anc,
    float* __restrict__ outp,
    f32x4* __restrict__ fillp, int n4, int nCompute, int gcols)
{
  __shared__ unsigned short sA[128 * 64], sB[128 * 64];  // 32 KiB
  const int bidx = blockIdx.x;
  if (bidx >= nCompute) {
    const f32x4 z = {0.f, 0.f, 0.f, 0.f};
    int i = (bidx - nCompute) * 256 + threadIdx.x;
    for (; i < n4; i += FILLB * 256) __builtin_nontemporal_store(z, fillp + i);
    return;
  }
  const int tid = threadIdx.x, lane = tid & 63, w = tid >> 6;
  const int wr = w >> 1, wc = w & 1;
  // bijective XCD swizzle (nCompute % 8 == 0)
  const unsigned int wg = ((unsigned)bidx & 7) * ((unsigned)nCompute >> 3) + ((unsigned)bidx >> 3);
  const int m0 = (int)(wg / gcols) * 128, n0 = (int)(wg % gcols) * 128;
  const int rsel = lane & 15, kg = lane >> 4;
  f32x4 acc[4][4] = {};

  for (int k0 = 0; k0 < DM; k0 += 64) {
    __syncthreads();
    // stage 1024 granules/array; granule g: row=g>>3, LDS slot=g&7 holds global
    // k-chunk (slot ^ (row&7))  [XOR bank swizzle]
    #pragma unroll
    for (int c = 0; c < 4; ++c) {
      const int gg = w * 256 + c * 64;           // wave-uniform granule base
      const int g = gg + lane;
      const int row = g >> 3, slot = g & 7;
      const int kk = k0 + ((slot ^ (row & 7)) << 3);
      gld_lds16(Ah + (size_t)(m0 + row) * DM + kk, sA + gg * 8);
      gld_lds16(Bh + (size_t)(n0 + row) * DM + kk, sB + gg * 8);
    }
    __syncthreads();
    #pragma unroll
    for (int s = 0; s < 2; ++s) {               // two K=32 sub-steps within BK=64
      s16x8 af[4], bf[4];
      #pragma unroll
      for (int i = 0; i < 4; ++i) {
        const int row = wr * 64 + i * 16 + rsel;
        const int as = (((s << 2) | kg) ^ (row & 7));
        af[i] = *reinterpret_cast<const s16x8*>(sA + row * 64 + as * 8);
        const int col = wc * 64 + i * 16 + rsel;
        const int bs = (((s << 2) | kg) ^ (col & 7));
        bf[i] = *reinterpret_cast<const s16x8*>(sB + col * 64 + bs * 8);
      }
      #pragma unroll
      for (int i = 0; i < 4; ++i)
        #pragma unroll
        for (int j = 0; j < 4; ++j)
          acc[i][j] = __builtin_amdgcn_mfma_f32_16x16x32_bf16(af[i], bf[j], acc[i][j], 0, 0, 0);
    }
  }

  #pragma unroll
  for (int i = 0; i < 4; ++i)
    #pragma unroll
    for (int j = 0; j < 4; ++j)
      #pragma unroll
      for (int r = 0; r < 4; ++r) {
        const int row = m0 + wr * 64 + i * 16 + kg * 4 + r;   // C/D: row=(l>>4)*4+reg
        const int col = n0 + wc * 64 + j * 16 + rsel;          //      col=l&15
        const float v = acc[i][j][r];
        const int b = row >> 9, a = row & (NA - 1);
        if (EPI == 1) {
          const int sec = (col >= 2 * DM) ? 2 : (col >= DM ? 1 : 0);
          const int f = col - sec * DM;
          const int hh = f / HDIM, d = f - hh * HDIM;
          const float* bp = (sec == 0) ? biasq : (sec == 1) ? biask : biasv;
          const float val = v + bp[f];
          const int bhh = b * NHEAD + hh;
          if (sec == 0) {
            const size_t o = ((size_t)bhh * NA + a) * HDIM + d; qh[o] = f2bf(val);
          } else if (sec == 1) {
            const size_t o = ((size_t)bhh * NA + a) * HDIM + d; kh[o] = f2bf(val);
          } else {
            const size_t o = ((size_t)bhh * HDIM + d) * NA + a; vh[o] = f2bf(val);  // V^T
          }
        } else {
          const int sidx = anc[b * NA + a];
          outp[((size_t)b * SEQ + sidx) * DM + col] = v + biaso[col];
        }
      }
}

// ---------------- fused attention: 32-row Q tiles, 64 KB LDS, 2 blocks/CU ----------
// XCD-aware mapping: all 16 Q-tiles of a (b,h) land on ONE XCD -> K/V L2-resident.
// QK^T 1-term bf16; fp32 softmax; PV 1-term; O bf16.
__global__ __launch_bounds__(512, 4) void attn_fused(
    const unsigned short* __restrict__ qh,
    const unsigned short* __restrict__ kh,
    const unsigned short* __restrict__ vh,
    unsigned short* __restrict__ oh)
{
  __shared__ unsigned int S[QBLK * 512];   // fp32 scores -> P bf16 (high16). 64 KiB
  __shared__ float rsum_lds[QBLK];
  // XCD mapping: xcd = blk&7 (dispatch round-robin); all qt of bh stay on xcd=bh%8.
  const int blk = blockIdx.x;
  const int xcd = blk & 7, slot = blk >> 3;
  const int qt = slot & 15, bh = (slot >> 4) * 8 + xcd;
  const int b = bh >> 3, h = bh & 7;
  const int tid = threadIdx.x, lane = tid & 63, w = tid >> 6;
  const int rt = w & 1, ctq = w >> 1;    // QK^T: rows rt*16.., ct in [ctq*8, ctq*8+8)
  const int rsel = lane & 15, kg = lane >> 4;
  const int q0 = qt * QBLK;

  // Q fragments for this wave's 16 rows (single bf16)
  s16x8 qf[3];
  {
    const size_t qrow = (size_t)bh * NA + q0 + rt * 16 + rsel;
    const unsigned short* qp = qh + qrow * HDIM + kg * 8;
    #pragma unroll
    for (int kc = 0; kc < 3; ++kc)
      qf[kc] = *reinterpret_cast<const s16x8*>(qp + kc * 32);
  }
  const float scale = 0.10206207261596575f;  // 1/sqrt(96)
  const unsigned short* kb_h = kh + (size_t)bh * NA * HDIM;

  for (int ct2 = 0; ct2 < 8; ++ct2) {
    const int ct = ctq * 8 + ct2;
    f32x4 acc = {0.f, 0.f, 0.f, 0.f};
    const unsigned short* kp = kb_h + (size_t)(ct * 16 + rsel) * HDIM + kg * 8;
    #pragma unroll
    for (int kc = 0; kc < 3; ++kc) {
      s16x8 kfh = *reinterpret_cast<const s16x8*>(kp + kc * 32);
      __builtin_amdgcn_s_setprio(1);
      acc = __builtin_amdgcn_mfma_f32_16x16x32_bf16(qf[kc], kfh, acc, 0, 0, 0);
      __builtin_amdgcn_s_setprio(0);
    }
    #pragma unroll
    for (int r = 0; r < 4; ++r) {
      int row = rt * 16 + kg * 4 + r;
      int col = ct * 16 + rsel;
      S[row * 512 + (col ^ ((row & 7) << 2))] = __float_as_uint(acc[r] * scale);
    }
  }
  __syncthreads();

  // softmax: wave w owns rows w*4..w*4+3; 16 lanes/row; interleaved cols (bank-floor)
  {
    const int row = w * 4 + (lane >> 4);
    const int sub = lane & 15;
    const int srow = (row & 7) << 2;
    unsigned int* rowp = &S[row * 512];
    float mx = -3.0e38f;
    #pragma unroll 8
    for (int i = 0; i < 8; ++i) {
      int c = sub * 4 + i * 64;
      uint4 u = *reinterpret_cast<const uint4*>(rowp + (c ^ srow));
      mx = fmaxf(mx, fmaxf(fmaxf(__uint_as_float(u.x), __uint_as_float(u.y)),
                           fmaxf(__uint_as_float(u.z), __uint_as_float(u.w))));
    }
    mx = fmaxf(mx, __shfl_xor(mx, 1));
    mx = fmaxf(mx, __shfl_xor(mx, 2));
    mx = fmaxf(mx, __shfl_xor(mx, 4));
    mx = fmaxf(mx, __shfl_xor(mx, 8));
    float sum = 0.f;
    #pragma unroll 8
    for (int i = 0; i < 8; ++i) {
      int c = sub * 4 + i * 64;
      uint4 u = *reinterpret_cast<const uint4*>(rowp + (c ^ srow));
      float p0 = __expf(__uint_as_float(u.x) - mx);
      float p1 = __expf(__uint_as_float(u.y) - mx);
      float p2 = __expf(__uint_as_float(u.z) - mx);
      float p3 = __expf(__uint_as_float(u.w) - mx);
      sum += p0 + p1 + p2 + p3;
      uint4 pk;
      pk.x = ((unsigned)f2bf(p0)) << 16;
      pk.y = ((unsigned)f2bf(p1)) << 16;
      pk.z = ((unsigned)f2bf(p2)) << 16;
      pk.w = ((unsigned)f2bf(p3)) << 16;
      *reinterpret_cast<uint4*>(rowp + (c ^ srow)) = pk;   // in-place, same lane
    }
    sum += __shfl_xor(sum, 1);
    sum += __shfl_xor(sum, 2);
    sum += __shfl_xor(sum, 4);
    sum += __shfl_xor(sum, 8);
    if (sub == 0) rsum_lds[row] = 1.f / sum;
  }
  __syncthreads();

  // O = P V : 12 tasks (rt2 x nt), round-robined over 8 waves; single-term
  const unsigned short* vb_h = vh + (size_t)bh * HDIM * NA;
  for (int task = w; task < 12; task += 8) {
    const int nt = task % 6, rt2 = task / 6;
    f32x4 acc = {0.f, 0.f, 0.f, 0.f};
    const int row = rt2 * 16 + rsel;
    const int srow = (row & 7) << 2;
    const unsigned int* rowp = &S[row * 512];
    for (int kc = 0; kc < 16; ++kc) {
      int c = kc * 32 + kg * 8;
      uint4 ua = *reinterpret_cast<const uint4*>(rowp + ((c) ^ srow));
      uint4 ub = *reinterpret_cast<const uint4*>(rowp + ((c + 4) ^ srow));
      s16x8 ph;
      ph[0] = (short)(ua.x >> 16); ph[1] = (short)(ua.y >> 16);
      ph[2] = (short)(ua.z >> 16); ph[3] = (short)(ua.w >> 16);
      ph[4] = (short)(ub.x >> 16); ph[5] = (short)(ub.y >> 16);
      ph[6] = (short)(ub.z >> 16); ph[7] = (short)(ub.w >> 16);
      const unsigned short* vp = vb_h + (size_t)(nt * 16 + rsel) * NA + c;
      s16x8 vfh = *reinterpret_cast<const s16x8*>(vp);
      __builtin_amdgcn_s_setprio(1);
      acc = __builtin_amdgcn_mfma_f32_16x16x32_bf16(ph, vfh, acc, 0, 0, 0);
      __builtin_amdgcn_s_setprio(0);
    }
    #pragma unroll
    for (int r = 0; r < 4; ++r) {
      const float rinv = rsum_lds[rt2 * 16 + kg * 4 + r];
      const int rowg = b * NA + q0 + rt2 * 16 + kg * 4 + r;
      size_t o = (size_t)rowg * DM + h * HDIM + nt * 16 + rsel;
      oh[o] = f2bf(acc[r] * rinv);
    }
  }
}

extern "C" void kernel_launch(void* const* d_in, const int* in_sizes, int n_in,
                              void* d_out, int out_size, void* d_ws, size_t ws_size,
                              hipStream_t stream)
{
  const float* hs   = (const float*)d_in[0];
  const int*   anc  = (const int*)d_in[1];
  const float* ln_g = (const float*)d_in[2];
  const float* ln_b = (const float*)d_in[3];
  const float* wq = (const float*)d_in[4];
  const float* bq = (const float*)d_in[5];
  const float* wk = (const float*)d_in[6];
  const float* bk = (const float*)d_in[7];
  const float* wv = (const float*)d_in[8];
  const float* bv = (const float*)d_in[9];
  const float* wo = (const float*)d_in[10];
  const float* bo = (const float*)d_in[11];
  float* outp = (float*)d_out;

  char* ws = (char*)d_ws;
  size_t off = 0;
  auto take = [&](size_t bytes) { char* p = ws + off; off += (bytes + 255) & ~(size_t)255; return p; };
  unsigned short* xh  = (unsigned short*)take((size_t)MROW * DM * 2);
  unsigned short* w1h = (unsigned short*)take((size_t)NQKV * DM * 2);
  unsigned short* woh = (unsigned short*)take((size_t)DM * DM * 2);
  const size_t qkvsz = (size_t)NB * NHEAD * NA * HDIM * 2;
  unsigned short* qhb = (unsigned short*)take(qkvsz);
  unsigned short* khb = (unsigned short*)take(qkvsz);
  unsigned short* vhb = (unsigned short*)take(qkvsz);
  unsigned short* ohb = (unsigned short*)take((size_t)MROW * DM * 2);

  prologue<<<MROW + 2304, 256, 0, stream>>>(
      hs, anc, ln_g, ln_b, wq, wk, wv, wo, xh, w1h, woh);
  gemm128<1><<<(MROW / 128) * (NQKV / 128) + FILLB, 256, 0, stream>>>(
      xh, w1h, bq, bk, bv, qhb, khb, vhb,
      nullptr, nullptr, nullptr,
      (f32x4*)outp, out_size / 4, (MROW / 128) * (NQKV / 128), NQKV / 128);
  attn_fused<<<NB * NHEAD * (NA / QBLK), 512, 0, stream>>>(
      qhb, khb, vhb, ohb);
  gemm128<2><<<(MROW / 128) * (DM / 128), 256, 0, stream>>>(
      ohb, woh, nullptr, nullptr, nullptr,
      nullptr, nullptr, nullptr,
      bo, anc, outp,
      nullptr, 0, (MROW / 128) * (DM / 128), DM / 128);
}

// Round 9
// 112.644 us; speedup vs baseline: 2.4480x; 1.0456x over previous
//
#include <hip/hip_runtime.h>

#define DM 768
#define NHEAD 8
#define HDIM 96
#define NB 8
#define SEQ 8192
#define NA 512
#define MROW (NB*NA)      // 4096 anchor rows total
#define NQKV (3*DM)       // 2304
#define QBLK 32
#define ATTNB 1024        // attn compute blocks
#define AFILLB 512        // fill blocks appended to attn grid
#define GFILLB 512        // fill blocks appended to gemm1 grid

typedef __attribute__((ext_vector_type(4))) float f32x4;
typedef __attribute__((ext_vector_type(8))) short s16x8;

static __device__ __forceinline__ unsigned short f2bf(float x) {
  unsigned int u = __float_as_uint(x);
  u += 0x7fffu + ((u >> 16) & 1u);          // RNE
  return (unsigned short)(u >> 16);
}

static __device__ __forceinline__ void gld_lds16(const void* g, void* l) {
  __builtin_amdgcn_global_load_lds(
      (const __attribute__((address_space(1))) unsigned int*)g,
      (__attribute__((address_space(3))) unsigned int*)l, 16, 0, 0);
}

// ---------------- prologue: weight f32->bf16 convert + gather+LN ----------------
__global__ __launch_bounds__(256) void prologue(
    const float* __restrict__ hs, const int* __restrict__ anc,
    const float* __restrict__ gam, const float* __restrict__ bet,
    const float* __restrict__ wq, const float* __restrict__ wk,
    const float* __restrict__ wv, const float* __restrict__ wo,
    unsigned short* __restrict__ xh,
    unsigned short* __restrict__ w1h, unsigned short* __restrict__ woh)
{
  __shared__ float red[8];
  const int bid = blockIdx.x;
  const int t = threadIdx.x;
  if (bid < MROW) {
    // ---- gather + LayerNorm -> single bf16 ----
    int r = bid;
    int b = r >> 9, a = r & (NA - 1);
    int idx = anc[b * NA + a];
    const float* src = hs + ((size_t)b * SEQ + idx) * DM;
    float e0 = src[t], e1 = src[t + 256], e2 = src[t + 512];
    float s = e0 + e1 + e2;
    float ss = e0*e0 + e1*e1 + e2*e2;
    #pragma unroll
    for (int o = 1; o < 64; o <<= 1) { s += __shfl_xor(s, o); ss += __shfl_xor(ss, o); }
    int w = t >> 6, lane = t & 63;
    if (lane == 0) { red[w] = s; red[4 + w] = ss; }
    __syncthreads();
    s  = red[0] + red[1] + red[2] + red[3];
    ss = red[4] + red[5] + red[6] + red[7];
    float mu = s * (1.f / DM);
    float var = ss * (1.f / DM) - mu * mu;   // biased, matches jnp.var
    float rstd = rsqrtf(var + 1e-5f);
    size_t base = (size_t)r * DM;
    #pragma unroll
    for (int p = 0; p < 3; ++p) {
      int c = t + p * 256;
      float e = (p == 0) ? e0 : (p == 1) ? e1 : e2;
      float y = (e - mu) * rstd * gam[c] + bet[c];
      xh[base + c] = f2bf(y);
    }
  } else {
    // ---- weight f32 -> bf16, float4-vectorized ----
    const int i = (bid - MROW) * 256 + t;    // float4 index
    const int T1_4 = (NQKV * DM) / 4;        // 442368
    const int TW_4 = (DM * DM) / 4;          // 147456
    float4 v;
    unsigned short* dh; int e4;
    if (i < T1_4) {
      v = (i < TW_4) ? reinterpret_cast<const float4*>(wq)[i]
        : (i < 2*TW_4) ? reinterpret_cast<const float4*>(wk)[i - TW_4]
                       : reinterpret_cast<const float4*>(wv)[i - 2*TW_4];
      dh = w1h; e4 = i;
    } else {
      int j = i - T1_4;
      v = reinterpret_cast<const float4*>(wo)[j];
      dh = woh; e4 = j;
    }
    uint2 ph;
    ph.x = (unsigned)f2bf(v.x) | ((unsigned)f2bf(v.y) << 16);
    ph.y = (unsigned)f2bf(v.z) | ((unsigned)f2bf(v.w) << 16);
    reinterpret_cast<uint2*>(dh)[e4] = ph;
  }
}

// ---------------- BMxBN single-bf16 NT GEMM template, BK=64 ----------------
// 4 waves, each (BM/2)x(BN/2) via MI x NJ 16x16 fragments. Blocks >= NCOMP fill.
// EPI=1: QKV epilogue (q/k/V^T bf16). EPI=2: scatter out.
template<int EPI, int BM, int BN, int NCOMP, int GCOLS>
__global__ __launch_bounds__(256, 4) void gemm_t(
    const unsigned short* __restrict__ Ah,
    const unsigned short* __restrict__ Bh,
    const float* __restrict__ biasq, const float* __restrict__ biask, const float* __restrict__ biasv,
    unsigned short* __restrict__ qh,
    unsigned short* __restrict__ kh,
    unsigned short* __restrict__ vh,
    const float* __restrict__ biaso, const int* __restrict__ anc,
    float* __restrict__ outp,
    f32x4* __restrict__ fillp, int fstart, int fend, int nfillb)
{
  constexpr int MI = BM / 32, NJ = BN / 32;
  __shared__ unsigned short sA[BM * 64], sB[BN * 64];
  const int bidx = blockIdx.x;
  if (bidx >= NCOMP) {
    const f32x4 z = {0.f, 0.f, 0.f, 0.f};
    int i = fstart + (bidx - NCOMP) * 256 + threadIdx.x;
    for (; i < fend; i += nfillb * 256) __builtin_nontemporal_store(z, fillp + i);
    return;
  }
  const int tid = threadIdx.x, lane = tid & 63, w = tid >> 6;
  const int wr = w >> 1, wc = w & 1;
  // bijective XCD swizzle (NCOMP % 8 == 0)
  const unsigned int wg = ((unsigned)bidx & 7) * (NCOMP >> 3) + ((unsigned)bidx >> 3);
  const int m0 = (int)(wg / GCOLS) * BM, n0 = (int)(wg % GCOLS) * BN;
  const int rsel = lane & 15, kg = lane >> 4;
  f32x4 acc[MI][NJ] = {};

  for (int k0 = 0; k0 < DM; k0 += 64) {
    __syncthreads();
    // (BM+BN)*8 granules of 16B; granule g: row=g>>3, LDS slot=g&7 holds global
    // k-chunk (slot ^ (row&7)). 64-granule chunks align to the A/B boundary
    // (BM*8 multiple of 64) so the branch is wave-uniform.
    #pragma unroll
    for (int c = 0; c < (BM + BN) / 32; ++c) {
      const int gg = c * 256 + w * 64;           // wave-uniform granule base
      const int g = gg + lane;
      if (g < BM * 8) {
        const int row = g >> 3, slot = g & 7;
        const int kk = k0 + ((slot ^ (row & 7)) << 3);
        gld_lds16(Ah + (size_t)(m0 + row) * DM + kk, sA + gg * 8);
      } else {
        const int g2 = g - BM * 8;
        const int row = g2 >> 3, slot = g2 & 7;
        const int kk = k0 + ((slot ^ (row & 7)) << 3);
        gld_lds16(Bh + (size_t)(n0 + row) * DM + kk, sB + (gg - BM * 8) * 8);
      }
    }
    __syncthreads();
    #pragma unroll
    for (int s = 0; s < 2; ++s) {               // two K=32 sub-steps within BK=64
      s16x8 af[MI], bf[NJ];
      #pragma unroll
      for (int i = 0; i < MI; ++i) {
        const int row = wr * (MI * 16) + i * 16 + rsel;
        const int as = (((s << 2) | kg) ^ (row & 7));
        af[i] = *reinterpret_cast<const s16x8*>(sA + row * 64 + as * 8);
      }
      #pragma unroll
      for (int j = 0; j < NJ; ++j) {
        const int col = wc * (NJ * 16) + j * 16 + rsel;
        const int bs = (((s << 2) | kg) ^ (col & 7));
        bf[j] = *reinterpret_cast<const s16x8*>(sB + col * 64 + bs * 8);
      }
      #pragma unroll
      for (int i = 0; i < MI; ++i)
        #pragma unroll
        for (int j = 0; j < NJ; ++j)
          acc[i][j] = __builtin_amdgcn_mfma_f32_16x16x32_bf16(af[i], bf[j], acc[i][j], 0, 0, 0);
    }
  }

  #pragma unroll
  for (int i = 0; i < MI; ++i)
    #pragma unroll
    for (int j = 0; j < NJ; ++j)
      #pragma unroll
      for (int r = 0; r < 4; ++r) {
        const int row = m0 + wr * (MI * 16) + i * 16 + kg * 4 + r;  // C/D: row=(l>>4)*4+reg
        const int col = n0 + wc * (NJ * 16) + j * 16 + rsel;         //      col=l&15
        const float v = acc[i][j][r];
        const int b = row >> 9, a = row & (NA - 1);
        if (EPI == 1) {
          const int sec = (col >= 2 * DM) ? 2 : (col >= DM ? 1 : 0);
          const int f = col - sec * DM;
          const int hh = f / HDIM, d = f - hh * HDIM;
          const float* bp = (sec == 0) ? biasq : (sec == 1) ? biask : biasv;
          const float val = v + bp[f];
          const int bhh = b * NHEAD + hh;
          if (sec == 0) {
            const size_t o = ((size_t)bhh * NA + a) * HDIM + d; qh[o] = f2bf(val);
          } else if (sec == 1) {
            const size_t o = ((size_t)bhh * NA + a) * HDIM + d; kh[o] = f2bf(val);
          } else {
            const size_t o = ((size_t)bhh * HDIM + d) * NA + a; vh[o] = f2bf(val);  // V^T
          }
        } else {
          const int sidx = anc[b * NA + a];
          outp[((size_t)b * SEQ + sidx) * DM + col] = v + biaso[col];
        }
      }
}

// ---------------- fused attention: 32-row Q tiles + fill tail ----------
// XCD-aware mapping: all 16 Q-tiles of a (b,h) land on ONE XCD -> K/V L2-resident.
// QK^T 1-term bf16; fp32 softmax; PV 1-term; O bf16. Blocks >= ATTNB zero-fill.
__global__ __launch_bounds__(512, 4) void attn_fused(
    const unsigned short* __restrict__ qh,
    const unsigned short* __restrict__ kh,
    const unsigned short* __restrict__ vh,
    unsigned short* __restrict__ oh,
    f32x4* __restrict__ fillp, int fstart, int fend)
{
  __shared__ unsigned int S[QBLK * 512];   // fp32 scores -> P bf16 (high16). 64 KiB
  __shared__ float rsum_lds[QBLK];
  if (blockIdx.x >= ATTNB) {
    const f32x4 z = {0.f, 0.f, 0.f, 0.f};
    int i = fstart + (blockIdx.x - ATTNB) * 512 + threadIdx.x;
    for (; i < fend; i += AFILLB * 512) __builtin_nontemporal_store(z, fillp + i);
    return;
  }
  // XCD mapping: xcd = blk&7 (dispatch round-robin); all qt of bh stay on xcd=bh%8.
  const int blk = blockIdx.x;
  const int xcd = blk & 7, slot = blk >> 3;
  const int qt = slot & 15, bh = (slot >> 4) * 8 + xcd;
  const int b = bh >> 3, h = bh & 7;
  const int tid = threadIdx.x, lane = tid & 63, w = tid >> 6;
  const int rt = w & 1, ctq = w >> 1;    // QK^T: rows rt*16.., ct in [ctq*8, ctq*8+8)
  const int rsel = lane & 15, kg = lane >> 4;
  const int q0 = qt * QBLK;

  // Q fragments for this wave's 16 rows (single bf16)
  s16x8 qf[3];
  {
    const size_t qrow = (size_t)bh * NA + q0 + rt * 16 + rsel;
    const unsigned short* qp = qh + qrow * HDIM + kg * 8;
    #pragma unroll
    for (int kc = 0; kc < 3; ++kc)
      qf[kc] = *reinterpret_cast<const s16x8*>(qp + kc * 32);
  }
  const float scale = 0.10206207261596575f;  // 1/sqrt(96)
  const unsigned short* kb_h = kh + (size_t)bh * NA * HDIM;

  for (int ct2 = 0; ct2 < 8; ++ct2) {
    const int ct = ctq * 8 + ct2;
    f32x4 acc = {0.f, 0.f, 0.f, 0.f};
    const unsigned short* kp = kb_h + (size_t)(ct * 16 + rsel) * HDIM + kg * 8;
    #pragma unroll
    for (int kc = 0; kc < 3; ++kc) {
      s16x8 kfh = *reinterpret_cast<const s16x8*>(kp + kc * 32);
      __builtin_amdgcn_s_setprio(1);
      acc = __builtin_amdgcn_mfma_f32_16x16x32_bf16(qf[kc], kfh, acc, 0, 0, 0);
      __builtin_amdgcn_s_setprio(0);
    }
    #pragma unroll
    for (int r = 0; r < 4; ++r) {
      int row = rt * 16 + kg * 4 + r;
      int col = ct * 16 + rsel;
      S[row * 512 + (col ^ ((row & 7) << 2))] = __float_as_uint(acc[r] * scale);
    }
  }
  __syncthreads();

  // softmax: wave w owns rows w*4..w*4+3; 16 lanes/row; interleaved cols (bank-floor)
  {
    const int row = w * 4 + (lane >> 4);
    const int sub = lane & 15;
    const int srow = (row & 7) << 2;
    unsigned int* rowp = &S[row * 512];
    float mx = -3.0e38f;
    #pragma unroll 8
    for (int i = 0; i < 8; ++i) {
      int c = sub * 4 + i * 64;
      uint4 u = *reinterpret_cast<const uint4*>(rowp + (c ^ srow));
      mx = fmaxf(mx, fmaxf(fmaxf(__uint_as_float(u.x), __uint_as_float(u.y)),
                           fmaxf(__uint_as_float(u.z), __uint_as_float(u.w))));
    }
    mx = fmaxf(mx, __shfl_xor(mx, 1));
    mx = fmaxf(mx, __shfl_xor(mx, 2));
    mx = fmaxf(mx, __shfl_xor(mx, 4));
    mx = fmaxf(mx, __shfl_xor(mx, 8));
    float sum = 0.f;
    #pragma unroll 8
    for (int i = 0; i < 8; ++i) {
      int c = sub * 4 + i * 64;
      uint4 u = *reinterpret_cast<const uint4*>(rowp + (c ^ srow));
      float p0 = __expf(__uint_as_float(u.x) - mx);
      float p1 = __expf(__uint_as_float(u.y) - mx);
      float p2 = __expf(__uint_as_float(u.z) - mx);
      float p3 = __expf(__uint_as_float(u.w) - mx);
      sum += p0 + p1 + p2 + p3;
      uint4 pk;
      pk.x = ((unsigned)f2bf(p0)) << 16;
      pk.y = ((unsigned)f2bf(p1)) << 16;
      pk.z = ((unsigned)f2bf(p2)) << 16;
      pk.w = ((unsigned)f2bf(p3)) << 16;
      *reinterpret_cast<uint4*>(rowp + (c ^ srow)) = pk;   // in-place, same lane
    }
    sum += __shfl_xor(sum, 1);
    sum += __shfl_xor(sum, 2);
    sum += __shfl_xor(sum, 4);
    sum += __shfl_xor(sum, 8);
    if (sub == 0) rsum_lds[row] = 1.f / sum;
  }
  __syncthreads();

  // O = P V : 12 tasks (rt2 x nt), round-robined over 8 waves; single-term
  const unsigned short* vb_h = vh + (size_t)bh * HDIM * NA;
  for (int task = w; task < 12; task += 8) {
    const int nt = task % 6, rt2 = task / 6;
    f32x4 acc = {0.f, 0.f, 0.f, 0.f};
    const int row = rt2 * 16 + rsel;
    const int srow = (row & 7) << 2;
    const unsigned int* rowp = &S[row * 512];
    for (int kc = 0; kc < 16; ++kc) {
      int c = kc * 32 + kg * 8;
      uint4 ua = *reinterpret_cast<const uint4*>(rowp + ((c) ^ srow));
      uint4 ub = *reinterpret_cast<const uint4*>(rowp + ((c + 4) ^ srow));
      s16x8 ph;
      ph[0] = (short)(ua.x >> 16); ph[1] = (short)(ua.y >> 16);
      ph[2] = (short)(ua.z >> 16); ph[3] = (short)(ua.w >> 16);
      ph[4] = (short)(ub.x >> 16); ph[5] = (short)(ub.y >> 16);
      ph[6] = (short)(ub.z >> 16); ph[7] = (short)(ub.w >> 16);
      const unsigned short* vp = vb_h + (size_t)(nt * 16 + rsel) * NA + c;
      s16x8 vfh = *reinterpret_cast<const s16x8*>(vp);
      __builtin_amdgcn_s_setprio(1);
      acc = __builtin_amdgcn_mfma_f32_16x16x32_bf16(ph, vfh, acc, 0, 0, 0);
      __builtin_amdgcn_s_setprio(0);
    }
    #pragma unroll
    for (int r = 0; r < 4; ++r) {
      const float rinv = rsum_lds[rt2 * 16 + kg * 4 + r];
      const int rowg = b * NA + q0 + rt2 * 16 + kg * 4 + r;
      size_t o = (size_t)rowg * DM + h * HDIM + nt * 16 + rsel;
      oh[o] = f2bf(acc[r] * rinv);
    }
  }
}

extern "C" void kernel_launch(void* const* d_in, const int* in_sizes, int n_in,
                              void* d_out, int out_size, void* d_ws, size_t ws_size,
                              hipStream_t stream)
{
  const float* hs   = (const float*)d_in[0];
  const int*   anc  = (const int*)d_in[1];
  const float* ln_g = (const float*)d_in[2];
  const float* ln_b = (const float*)d_in[3];
  const float* wq = (const float*)d_in[4];
  const float* bq = (const float*)d_in[5];
  const float* wk = (const float*)d_in[6];
  const float* bk = (const float*)d_in[7];
  const float* wv = (const float*)d_in[8];
  const float* bv = (const float*)d_in[9];
  const float* wo = (const float*)d_in[10];
  const float* bo = (const float*)d_in[11];
  float* outp = (float*)d_out;

  char* ws = (char*)d_ws;
  size_t off = 0;
  auto take = [&](size_t bytes) { char* p = ws + off; off += (bytes + 255) & ~(size_t)255; return p; };
  unsigned short* xh  = (unsigned short*)take((size_t)MROW * DM * 2);
  unsigned short* w1h = (unsigned short*)take((size_t)NQKV * DM * 2);
  unsigned short* woh = (unsigned short*)take((size_t)DM * DM * 2);
  const size_t qkvsz = (size_t)NB * NHEAD * NA * HDIM * 2;
  unsigned short* qhb = (unsigned short*)take(qkvsz);
  unsigned short* khb = (unsigned short*)take(qkvsz);
  unsigned short* vhb = (unsigned short*)take(qkvsz);
  unsigned short* ohb = (unsigned short*)take((size_t)MROW * DM * 2);

  const int n4 = out_size / 4;
  const int fb = (int)(((long long)n4 * 5) / 8);   // gemm1 fills [0,fb), attn [fb,n4)

  prologue<<<MROW + 2304, 256, 0, stream>>>(
      hs, anc, ln_g, ln_b, wq, wk, wv, wo, xh, w1h, woh);
  // gemm1: 128x96 tiles -> 32*24 = 768 compute blocks (3/CU balanced) + 512 fill
  gemm_t<1, 128, 96, 768, 24><<<768 + GFILLB, 256, 0, stream>>>(
      xh, w1h, bq, bk, bv, qhb, khb, vhb,
      nullptr, nullptr, nullptr,
      (f32x4*)outp, 0, fb, GFILLB);
  attn_fused<<<ATTNB + AFILLB, 512, 0, stream>>>(
      qhb, khb, vhb, ohb, (f32x4*)outp, fb, n4);
  // gemm2: 64x96 tiles -> 64*8 = 512 compute blocks (2/CU balanced)
  gemm_t<2, 64, 96, 512, 8><<<512, 256, 0, stream>>>(
      ohb, woh, nullptr, nullptr, nullptr,
      nullptr, nullptr, nullptr,
      bo, anc, outp,
      nullptr, 0, 0, 1);
}